// Round 1
// baseline (1239.831 us; speedup 1.0000x reference)
//
#include <hip/hip_runtime.h>
#include <math.h>

#define HID 128
#define GRP 256
#define INF 9
#define OUTF 10

// ---------------- degree histogram over dst ----------------
__global__ void hist_kernel(const int* __restrict__ ei, int* __restrict__ cnt, int E) {
    int e = blockIdx.x * blockDim.x + threadIdx.x;
    if (e < E) atomicAdd(&cnt[ei[E + e]], 1);
}

// ---------------- single-block exclusive scan (+dinv) ----------------
__global__ __launch_bounds__(1024) void scan_kernel(const int* __restrict__ cnt,
                                                    int* __restrict__ row_ptr,
                                                    float* __restrict__ dinv, int n) {
    __shared__ int warp_sums[16];
    __shared__ int chunk_carry;
    int tid = threadIdx.x;
    int lane = tid & 63, wid = tid >> 6;
    if (tid == 0) chunk_carry = 0;
    __syncthreads();
    for (int base = 0; base < n; base += 4096) {
        int idx0 = base + tid * 4;
        int v[4];
        #pragma unroll
        for (int i = 0; i < 4; i++) v[i] = (idx0 + i < n) ? cnt[idx0 + i] : 0;
        int s = v[0] + v[1] + v[2] + v[3];
        int ps = s;
        #pragma unroll
        for (int off = 1; off < 64; off <<= 1) {
            int t = __shfl_up(ps, off);
            if (lane >= off) ps += t;
        }
        if (lane == 63) warp_sums[wid] = ps;
        __syncthreads();
        if (wid == 0 && lane < 16) {
            int ws = warp_sums[lane];
            #pragma unroll
            for (int off = 1; off < 16; off <<= 1) {
                int t = __shfl_up(ws, off);
                if (lane >= off) ws += t;
            }
            warp_sums[lane] = ws;
        }
        __syncthreads();
        int offset = chunk_carry + (wid > 0 ? warp_sums[wid - 1] : 0) + (ps - s);
        int run = offset;
        #pragma unroll
        for (int i = 0; i < 4; i++) {
            if (idx0 + i < n) {
                row_ptr[idx0 + i] = run;
                dinv[idx0 + i] = rsqrtf((float)(v[i] + 1));
                run += v[i];
            }
        }
        __syncthreads();
        if (tid == 0) chunk_carry += warp_sums[15];
        __syncthreads();
    }
    if (tid == 0) row_ptr[n] = chunk_carry;
}

// ---------------- CSR fill ----------------
__global__ void fill_kernel(const int* __restrict__ ei, const int* __restrict__ row_ptr,
                            int* __restrict__ cursor, const float* __restrict__ dinv,
                            int* __restrict__ csr_src, float* __restrict__ csr_coef, int E) {
    int e = blockIdx.x * blockDim.x + threadIdx.x;
    if (e >= E) return;
    int s = ei[e], d = ei[E + e];
    int pos = row_ptr[d] + atomicAdd(&cursor[d], 1);
    csr_src[pos] = s;
    csr_coef[pos] = dinv[s] * dinv[d];
}

// ---------------- graph boundary detection (batch is sorted) ----------------
__global__ void bounds_kernel(const int* __restrict__ batch, int* __restrict__ gstart,
                              int* __restrict__ gend, int n) {
    int i = blockIdx.x * blockDim.x + threadIdx.x;
    if (i >= n) return;
    int b = batch[i];
    if (i == 0 || batch[i - 1] != b) gstart[b] = i;
    if (i == n - 1 || batch[i + 1] != b) gend[b] = i + 1;
}

// ---------------- layer-0 GEMM: h = x(N x 9) @ W0(9 x 128) ----------------
__global__ __launch_bounds__(256) void gemm0_kernel(const float* __restrict__ x,
                                                    const float* __restrict__ W0,
                                                    float* __restrict__ h, int n) {
    __shared__ float Ws[INF * HID];
    __shared__ float xs[2 * INF];
    int tid = threadIdx.x;
    for (int i = tid; i < INF * HID; i += 256) Ws[i] = W0[i];
    if (tid < 2 * INF) {
        int nn = blockIdx.x * 2 + tid / INF;
        xs[tid] = (nn < n) ? x[nn * INF + tid % INF] : 0.0f;
    }
    __syncthreads();
    int node = blockIdx.x * 2 + (tid >> 7);
    int c = tid & 127;
    if (node >= n) return;
    const float* xr = xs + (tid >> 7) * INF;
    float acc = 0.0f;
    #pragma unroll
    for (int k = 0; k < INF; k++) acc = fmaf(xr[k], Ws[k * HID + c], acc);
    h[node * HID + c] = acc;
}

// ---------------- GEMM with fused input BN affine: out = (w*in+u) @ W ----------------
// 64-row x 128-col tile, 256 threads, 8x4 outputs per thread.
__global__ __launch_bounds__(256) void gemm_bn_kernel(const float* __restrict__ in,
                                                      const float* __restrict__ W,
                                                      const float* __restrict__ bnw,
                                                      const float* __restrict__ bnu,
                                                      float* __restrict__ out, int n) {
    __shared__ float As[HID * 68];   // transposed: As[k*68 + r], padded
    __shared__ float Bs[32 * HID];   // k-chunk of W
    int tid = threadIdx.x;
    int r0 = blockIdx.x * 64;
    #pragma unroll
    for (int i = 0; i < 32; i++) {
        int idx = tid + i * 256;
        int r = idx >> 7, c = idx & 127;
        int gr = r0 + r;
        float v = (gr < n) ? in[gr * HID + c] : 0.0f;
        As[c * 68 + r] = fmaf(bnw[c], v, bnu[c]);
    }
    int tc = (tid & 31) << 2;
    int tr = (tid >> 5) << 3;
    float acc[8][4];
    #pragma unroll
    for (int i = 0; i < 8; i++)
        #pragma unroll
        for (int j = 0; j < 4; j++) acc[i][j] = 0.0f;
    for (int kk = 0; kk < HID; kk += 32) {
        __syncthreads();
        #pragma unroll
        for (int i = 0; i < 16; i++) {
            int idx = tid + i * 256;
            int k = idx >> 7, c = idx & 127;
            Bs[k * HID + c] = W[(kk + k) * HID + c];
        }
        __syncthreads();
        #pragma unroll
        for (int k = 0; k < 32; k++) {
            const float4 b4 = *(const float4*)&Bs[k * HID + tc];
            const float4 a0 = *(const float4*)&As[(kk + k) * 68 + tr];
            const float4 a1 = *(const float4*)&As[(kk + k) * 68 + tr + 4];
            float av[8] = {a0.x, a0.y, a0.z, a0.w, a1.x, a1.y, a1.z, a1.w};
            float bv[4] = {b4.x, b4.y, b4.z, b4.w};
            #pragma unroll
            for (int i = 0; i < 8; i++)
                #pragma unroll
                for (int j = 0; j < 4; j++) acc[i][j] = fmaf(av[i], bv[j], acc[i][j]);
        }
    }
    #pragma unroll
    for (int i = 0; i < 8; i++) {
        int gr = r0 + tr + i;
        if (gr < n) {
            float4 o = make_float4(acc[i][0], acc[i][1], acc[i][2], acc[i][3]);
            *(float4*)&out[gr * HID + tc] = o;
        }
    }
}

// ---------------- aggregate + bias + rational activation ----------------
__global__ __launch_bounds__(256) void agg_kernel(const float* __restrict__ h,
                                                  const int* __restrict__ row_ptr,
                                                  const int* __restrict__ csr_src,
                                                  const float* __restrict__ csr_coef,
                                                  const float* __restrict__ dinv,
                                                  const float* __restrict__ bias,
                                                  const float* __restrict__ rat_num,
                                                  const float* __restrict__ rat_den,
                                                  const int* __restrict__ cl_assign,
                                                  float* __restrict__ act, int n) {
    __shared__ float s_num[120];
    __shared__ float s_den[80];
    __shared__ int s_cl[HID];
    int tid = threadIdx.x;
    if (tid < 120) s_num[tid] = rat_num[tid];
    if (tid >= 128 && tid < 208) s_den[tid - 128] = rat_den[tid - 128];
    if (tid < HID) s_cl[tid] = cl_assign[tid];
    __syncthreads();
    int node = blockIdx.x * 2 + (tid >> 7);
    int c = tid & 127;
    if (node >= n) return;
    float di = dinv[node];
    float acc = h[node * HID + c] * (di * di);
    int beg = row_ptr[node], end = row_ptr[node + 1];
    for (int j = beg; j < end; j++) {
        int s = csr_src[j];
        float cf = csr_coef[j];
        acc = fmaf(cf, h[s * HID + c], acc);
    }
    float xv = acc + bias[c];
    int cl = s_cl[c];
    const float* a = s_num + cl * 6;
    const float* q = s_den + cl * 4;
    float P = a[5];
    P = fmaf(P, xv, a[4]); P = fmaf(P, xv, a[3]); P = fmaf(P, xv, a[2]);
    P = fmaf(P, xv, a[1]); P = fmaf(P, xv, a[0]);
    float Q = q[3];
    Q = fmaf(Q, xv, q[2]); Q = fmaf(Q, xv, q[1]); Q = fmaf(Q, xv, q[0]);
    Q *= xv;
    act[node * HID + c] = P / (1.0f + fabsf(Q));
}

// ---------------- BN statistics (sum, sumsq per channel) ----------------
__global__ __launch_bounds__(256) void bn_stats_kernel(const float* __restrict__ act,
                                                       float* __restrict__ stat, int n) {
    __shared__ float ls[256], ls2[256];
    int tid = threadIdx.x;
    int c = tid & 127, half = tid >> 7;
    float s = 0.0f, s2 = 0.0f;
    for (int r = blockIdx.x * 2 + half; r < n; r += gridDim.x * 2) {
        float v = act[r * HID + c];
        s += v; s2 = fmaf(v, v, s2);
    }
    ls[tid] = s; ls2[tid] = s2;
    __syncthreads();
    if (tid < HID) {
        atomicAdd(&stat[c], ls[tid] + ls[tid + 128]);
        atomicAdd(&stat[HID + c], ls2[tid] + ls2[tid + 128]);
    }
}

__global__ void bn_finalize_kernel(const float* __restrict__ stat, const float* __restrict__ g,
                                   const float* __restrict__ be, float* __restrict__ bnw,
                                   float* __restrict__ bnu, int n) {
    int c = threadIdx.x;
    float inv_n = 1.0f / (float)n;
    float mean = stat[c] * inv_n;
    float var = stat[HID + c] * inv_n - mean * mean;
    float w = g[c] * rsqrtf(var + 1e-5f);
    bnw[c] = w;
    bnu[c] = be[c] - mean * w;
}

// ---------------- pooling by graph (boundaries, no atomics) ----------------
__global__ void pool_kernel(const float* __restrict__ act, const int* __restrict__ gstart,
                            const int* __restrict__ gend, const float* __restrict__ bnw,
                            const float* __restrict__ bnu, float* __restrict__ pooledf) {
    int g = blockIdx.x, c = threadIdx.x;
    int s = gstart[g], e = gend[g];
    float acc = 0.0f;
    for (int r = s; r < e; r++) acc += act[r * HID + c];
    int cnt = e - s;
    pooledf[g * HID + c] = (cnt > 0) ? fmaf(bnw[c], acc / (float)cnt, bnu[c]) : 0.0f;
}

// ---------------- MLP ----------------
__global__ void mlp_gelu_kernel(const float* __restrict__ in, const float* __restrict__ W,
                                const float* __restrict__ b, float* __restrict__ out) {
    __shared__ float rs[HID];
    int g = blockIdx.x, c = threadIdx.x;
    rs[c] = in[g * HID + c];
    __syncthreads();
    float acc = b[c];
    #pragma unroll 8
    for (int k = 0; k < HID; k++) acc = fmaf(rs[k], W[k * HID + c], acc);
    out[g * HID + c] = 0.5f * acc * (1.0f + erff(acc * 0.70710678118654752f));
}

__global__ void mlp_out_kernel(const float* __restrict__ in, const float* __restrict__ W,
                               const float* __restrict__ b, float* __restrict__ out) {
    __shared__ float rs[HID];
    int g = blockIdx.x, c = threadIdx.x;
    rs[c] = in[g * HID + c];
    __syncthreads();
    if (c < OUTF) {
        float acc = b[c];
        #pragma unroll 8
        for (int k = 0; k < HID; k++) acc = fmaf(rs[k], W[k * OUTF + c], acc);
        out[g * OUTF + c] = acc;
    }
}

extern "C" void kernel_launch(void* const* d_in, const int* in_sizes, int n_in,
                              void* d_out, int out_size, void* d_ws, size_t ws_size,
                              hipStream_t stream) {
    const float* x          = (const float*)d_in[0];
    const int*   edge_index = (const int*)d_in[1];
    const int*   batch      = (const int*)d_in[2];
    const float* W[4]  = {(const float*)d_in[3], (const float*)d_in[7], (const float*)d_in[11], (const float*)d_in[15]};
    const float* bL[4] = {(const float*)d_in[4], (const float*)d_in[8], (const float*)d_in[12], (const float*)d_in[16]};
    const float* gL[4] = {(const float*)d_in[5], (const float*)d_in[9], (const float*)d_in[13], (const float*)d_in[17]};
    const float* beL[4]= {(const float*)d_in[6], (const float*)d_in[10], (const float*)d_in[14], (const float*)d_in[18]};
    const float* rat_num = (const float*)d_in[19];
    const float* rat_den = (const float*)d_in[20];
    const int*   cl_assign = (const int*)d_in[21];
    const float* HW1 = (const float*)d_in[22];
    const float* Hb1 = (const float*)d_in[23];
    const float* HW2 = (const float*)d_in[24];
    const float* Hb2 = (const float*)d_in[25];
    const float* HW3 = (const float*)d_in[26];
    const float* Hb3 = (const float*)d_in[27];
    float* out = (float*)d_out;

    const int N = in_sizes[0] / INF;
    const int E = in_sizes[1] / 2;

    // ---- workspace layout (element offsets; all 4-byte elems) ----
    char* wsb = (char*)d_ws;
    size_t o = 0;
    int*   cnt     = (int*)(wsb + o * 4);  o += N;          // zeroed
    int*   cursor  = (int*)(wsb + o * 4);  o += N;          // zeroed
    int*   gstart  = (int*)(wsb + o * 4);  o += GRP;        // zeroed
    int*   gend    = (int*)(wsb + o * 4);  o += GRP;        // zeroed
    float* bnstat  = (float*)(wsb + o * 4); o += 4 * 256;   // zeroed (4 layers x [sum|sq])
    size_t zero_elems = o;
    int*   row_ptr = (int*)(wsb + o * 4);  o += N + 1;
    o = (o + 3) & ~(size_t)3;
    float* dinv    = (float*)(wsb + o * 4); o += N;
    int*   csr_src = (int*)(wsb + o * 4);   o += E;
    float* csr_coef= (float*)(wsb + o * 4); o += E;
    float* bnw     = (float*)(wsb + o * 4); o += 4 * HID;
    float* bnu     = (float*)(wsb + o * 4); o += 4 * HID;
    float* pooledf = (float*)(wsb + o * 4); o += GRP * HID;
    float* z1      = (float*)(wsb + o * 4); o += GRP * HID;
    float* z2      = (float*)(wsb + o * 4); o += GRP * HID;
    o = (o + 3) & ~(size_t)3;
    float* h       = (float*)(wsb + o * 4); o += (size_t)N * HID;
    float* act     = (float*)(wsb + o * 4); o += (size_t)N * HID;

    hipMemsetAsync(d_ws, 0, zero_elems * 4, stream);

    int eb = (E + 255) / 256;
    hist_kernel<<<eb, 256, 0, stream>>>(edge_index, cnt, E);
    scan_kernel<<<1, 1024, 0, stream>>>(cnt, row_ptr, dinv, N);
    fill_kernel<<<eb, 256, 0, stream>>>(edge_index, row_ptr, cursor, dinv, csr_src, csr_coef, E);
    bounds_kernel<<<(N + 255) / 256, 256, 0, stream>>>(batch, gstart, gend, N);

    int nb2 = (N + 1) / 2;
    int gemm_grid = (N + 63) / 64;

    gemm0_kernel<<<nb2, 256, 0, stream>>>(x, W[0], h, N);
    for (int l = 0; l < 4; l++) {
        if (l > 0) {
            gemm_bn_kernel<<<gemm_grid, 256, 0, stream>>>(act, W[l], bnw + (l - 1) * HID,
                                                          bnu + (l - 1) * HID, h, N);
        }
        agg_kernel<<<nb2, 256, 0, stream>>>(h, row_ptr, csr_src, csr_coef, dinv, bL[l],
                                            rat_num, rat_den, cl_assign, act, N);
        bn_stats_kernel<<<256, 256, 0, stream>>>(act, bnstat + l * 256, N);
        bn_finalize_kernel<<<1, HID, 0, stream>>>(bnstat + l * 256, gL[l], beL[l],
                                                  bnw + l * HID, bnu + l * HID, N);
    }
    pool_kernel<<<GRP, HID, 0, stream>>>(act, gstart, gend, bnw + 3 * HID, bnu + 3 * HID, pooledf);
    mlp_gelu_kernel<<<GRP, HID, 0, stream>>>(pooledf, HW1, Hb1, z1);
    mlp_gelu_kernel<<<GRP, HID, 0, stream>>>(z1, HW2, Hb2, z2);
    mlp_out_kernel<<<GRP, HID, 0, stream>>>(z2, HW3, Hb3, out);
}

// Round 2
// 786.560 us; speedup vs baseline: 1.5763x; 1.5763x over previous
//
#include <hip/hip_runtime.h>
#include <math.h>

#define HID 128
#define GRP 256
#define INF 9
#define OUTF 10

// ---------------- degree histogram over dst ----------------
__global__ void hist_kernel(const int* __restrict__ ei, int* __restrict__ cnt, int E) {
    int e = blockIdx.x * blockDim.x + threadIdx.x;
    if (e < E) atomicAdd(&cnt[ei[E + e]], 1);
}

// ---------------- single-block exclusive scan (+dinv); writes row_ptr AND cursor ----------------
__global__ __launch_bounds__(1024) void scan_kernel(const int* __restrict__ cnt,
                                                    int* __restrict__ row_ptr,
                                                    int* __restrict__ cursor,
                                                    float* __restrict__ dinv, int n) {
    __shared__ int warp_sums[16];
    __shared__ int chunk_carry;
    int tid = threadIdx.x;
    int lane = tid & 63, wid = tid >> 6;
    if (tid == 0) chunk_carry = 0;
    __syncthreads();
    for (int base = 0; base < n; base += 4096) {
        int idx0 = base + tid * 4;
        int v[4];
        #pragma unroll
        for (int i = 0; i < 4; i++) v[i] = (idx0 + i < n) ? cnt[idx0 + i] : 0;
        int s = v[0] + v[1] + v[2] + v[3];
        int ps = s;
        #pragma unroll
        for (int off = 1; off < 64; off <<= 1) {
            int t = __shfl_up(ps, off);
            if (lane >= off) ps += t;
        }
        if (lane == 63) warp_sums[wid] = ps;
        __syncthreads();
        if (wid == 0 && lane < 16) {
            int ws = warp_sums[lane];
            #pragma unroll
            for (int off = 1; off < 16; off <<= 1) {
                int t = __shfl_up(ws, off);
                if (lane >= off) ws += t;
            }
            warp_sums[lane] = ws;
        }
        __syncthreads();
        int offset = chunk_carry + (wid > 0 ? warp_sums[wid - 1] : 0) + (ps - s);
        int run = offset;
        #pragma unroll
        for (int i = 0; i < 4; i++) {
            if (idx0 + i < n) {
                row_ptr[idx0 + i] = run;
                cursor[idx0 + i] = run;
                dinv[idx0 + i] = rsqrtf((float)(v[i] + 1));
                run += v[i];
            }
        }
        __syncthreads();
        if (tid == 0) chunk_carry += warp_sums[15];
        __syncthreads();
    }
    if (tid == 0) row_ptr[n] = chunk_carry;
}

// ---------------- CSR fill (cursor pre-initialized to row starts) ----------------
__global__ void fill_kernel(const int* __restrict__ ei, int* __restrict__ cursor,
                            const float* __restrict__ dinv,
                            int* __restrict__ csr_src, float* __restrict__ csr_coef, int E) {
    int e = blockIdx.x * blockDim.x + threadIdx.x;
    if (e >= E) return;
    int s = ei[e], d = ei[E + e];
    int pos = atomicAdd(&cursor[d], 1);
    csr_src[pos] = s;
    csr_coef[pos] = dinv[s] * dinv[d];
}

// ---------------- graph boundary detection (batch is sorted) ----------------
__global__ void bounds_kernel(const int* __restrict__ batch, int* __restrict__ gstart,
                              int* __restrict__ gend, int n) {
    int i = blockIdx.x * blockDim.x + threadIdx.x;
    if (i >= n) return;
    int b = batch[i];
    if (i == 0 || batch[i - 1] != b) gstart[b] = i;
    if (i == n - 1 || batch[i + 1] != b) gend[b] = i + 1;
}

// ---------------- rational activation ----------------
__device__ __forceinline__ float rational_act(float xv, const float* __restrict__ a,
                                              const float* __restrict__ q) {
    float P = a[5];
    P = fmaf(P, xv, a[4]); P = fmaf(P, xv, a[3]); P = fmaf(P, xv, a[2]);
    P = fmaf(P, xv, a[1]); P = fmaf(P, xv, a[0]);
    float Q = q[3];
    Q = fmaf(Q, xv, q[2]); Q = fmaf(Q, xv, q[1]); Q = fmaf(Q, xv, q[0]);
    Q *= xv;
    return P / (1.0f + fabsf(Q));
}

// ---------------- aggregate x (9 channels) + cagg ----------------
__global__ __launch_bounds__(256) void aggx_kernel(const float* __restrict__ x,
                                                   const int* __restrict__ row_ptr,
                                                   const int* __restrict__ csr_src,
                                                   const float* __restrict__ csr_coef,
                                                   const float* __restrict__ dinv,
                                                   float* __restrict__ aggX,
                                                   float* __restrict__ cagg, int n) {
    int tid = threadIdx.x;
    int node = blockIdx.x * 16 + (tid >> 4);
    int lane = tid & 15;
    if (node >= n) return;
    float di = dinv[node];
    float self = di * di;
    float acc = (lane < INF) ? x[node * INF + lane] * self : 0.0f;
    float cfs = self;
    int beg = row_ptr[node], end = row_ptr[node + 1];
    for (int j = beg; j < end; j++) {
        int s = csr_src[j];
        float cf = csr_coef[j];
        cfs += cf;
        if (lane < INF) acc = fmaf(cf, x[s * INF + lane], acc);
    }
    if (lane < INF) aggX[node * INF + lane] = acc;
    if (lane == 0) cagg[node] = cfs;
}

// ---------------- layer-0: aggX(Nx9) @ W0 + b0 -> rational -> act + stats ----------------
__global__ __launch_bounds__(256) void gemm0_fused_kernel(const float* __restrict__ aggX,
                                                          const float* __restrict__ W0,
                                                          const float* __restrict__ b0,
                                                          const float* __restrict__ rat_num,
                                                          const float* __restrict__ rat_den,
                                                          const int* __restrict__ cl_assign,
                                                          float* __restrict__ act,
                                                          float* __restrict__ stat, int n) {
    __shared__ float Ws[INF * HID];
    __shared__ float s_num[120], s_den[80];
    __shared__ int s_cl[HID];
    __shared__ float s_b[HID];
    __shared__ float s_sum[HID], s_sq[HID];
    int tid = threadIdx.x;
    for (int i = tid; i < INF * HID; i += 256) Ws[i] = W0[i];
    if (tid < 120) s_num[tid] = rat_num[tid];
    if (tid < 80) s_den[tid] = rat_den[tid];
    if (tid < HID) {
        s_cl[tid] = cl_assign[tid];
        s_b[tid] = b0[tid];
        s_sum[tid] = 0.0f; s_sq[tid] = 0.0f;
    }
    __syncthreads();
    int c = tid & 127;
    int half = tid >> 7;
    const float* a = s_num + s_cl[c] * 6;
    const float* q = s_den + s_cl[c] * 4;
    float psum = 0.0f, psq = 0.0f;
    for (int node = blockIdx.x * 2 + half; node < n; node += gridDim.x * 2) {
        float acc = s_b[c];
        #pragma unroll
        for (int k = 0; k < INF; k++) acc = fmaf(aggX[node * INF + k], Ws[k * HID + c], acc);
        float r = rational_act(acc, a, q);
        act[node * HID + c] = r;
        psum += r; psq = fmaf(r, r, psq);
    }
    atomicAdd(&s_sum[c], psum);
    atomicAdd(&s_sq[c], psq);
    __syncthreads();
    if (tid < HID) {
        atomicAdd(&stat[tid], s_sum[tid]);
        atomicAdd(&stat[HID + tid], s_sq[tid]);
    }
}

// ---------------- gather-aggregate act (128 ch, float4, LDS-staged indices) ----------------
__global__ __launch_bounds__(256) void agg_kernel(const float4* __restrict__ act4,
                                                  const int* __restrict__ row_ptr,
                                                  const int* __restrict__ csr_src,
                                                  const float* __restrict__ csr_coef,
                                                  const float* __restrict__ dinv,
                                                  float4* __restrict__ aggY4, int n) {
    __shared__ int s_src[8][32];
    __shared__ float s_cf[8][32];
    int tid = threadIdx.x;
    int row = tid >> 5, lane = tid & 31;
    int node = blockIdx.x * 8 + row;
    if (node >= n) return;
    float di = dinv[node];
    float selfc = di * di;
    float4 a = act4[node * 32 + lane];
    float4 acc;
    acc.x = a.x * selfc; acc.y = a.y * selfc; acc.z = a.z * selfc; acc.w = a.w * selfc;
    int beg = row_ptr[node], end = row_ptr[node + 1];
    for (int base = beg; base < end; base += 32) {
        int m = end - base; if (m > 32) m = 32;
        if (lane < m) {
            s_src[row][lane] = csr_src[base + lane];
            s_cf[row][lane] = csr_coef[base + lane];
        }
        __builtin_amdgcn_wave_barrier();
        int j = 0;
        for (; j + 4 <= m; j += 4) {
            int s0 = s_src[row][j], s1 = s_src[row][j + 1];
            int s2 = s_src[row][j + 2], s3 = s_src[row][j + 3];
            float c0 = s_cf[row][j], c1 = s_cf[row][j + 1];
            float c2 = s_cf[row][j + 2], c3 = s_cf[row][j + 3];
            float4 v0 = act4[s0 * 32 + lane];
            float4 v1 = act4[s1 * 32 + lane];
            float4 v2 = act4[s2 * 32 + lane];
            float4 v3 = act4[s3 * 32 + lane];
            acc.x = fmaf(c0, v0.x, acc.x); acc.y = fmaf(c0, v0.y, acc.y);
            acc.z = fmaf(c0, v0.z, acc.z); acc.w = fmaf(c0, v0.w, acc.w);
            acc.x = fmaf(c1, v1.x, acc.x); acc.y = fmaf(c1, v1.y, acc.y);
            acc.z = fmaf(c1, v1.z, acc.z); acc.w = fmaf(c1, v1.w, acc.w);
            acc.x = fmaf(c2, v2.x, acc.x); acc.y = fmaf(c2, v2.y, acc.y);
            acc.z = fmaf(c2, v2.z, acc.z); acc.w = fmaf(c2, v2.w, acc.w);
            acc.x = fmaf(c3, v3.x, acc.x); acc.y = fmaf(c3, v3.y, acc.y);
            acc.z = fmaf(c3, v3.z, acc.z); acc.w = fmaf(c3, v3.w, acc.w);
        }
        for (; j < m; j++) {
            int s = s_src[row][j];
            float cf = s_cf[row][j];
            float4 v = act4[s * 32 + lane];
            acc.x = fmaf(cf, v.x, acc.x); acc.y = fmaf(cf, v.y, acc.y);
            acc.z = fmaf(cf, v.z, acc.z); acc.w = fmaf(cf, v.w, acc.w);
        }
    }
    aggY4[node * 32 + lane] = acc;
}

// ---------------- fused GEMM for layers 1-3 ----------------
// in = bnw (.) aggY + bnu * cagg[row];  out_pre = in @ W + bias;  act = rational(out_pre); stats.
__global__ __launch_bounds__(256) void gemm_fused_kernel(const float* __restrict__ aggY,
                                                         const float* __restrict__ W,
                                                         const float* __restrict__ bias,
                                                         const float* __restrict__ bnw,
                                                         const float* __restrict__ bnu,
                                                         const float* __restrict__ cagg,
                                                         const float* __restrict__ rat_num,
                                                         const float* __restrict__ rat_den,
                                                         const int* __restrict__ cl_assign,
                                                         float* __restrict__ act,
                                                         float* __restrict__ stat, int n) {
    __shared__ float As[HID * 68];   // As[c*68 + r]
    __shared__ float Bs[32 * HID];
    __shared__ float s_cagg[64];
    __shared__ float s_num[120], s_den[80];
    __shared__ int s_cl[HID];
    __shared__ float s_sum[HID], s_sq[HID];
    int tid = threadIdx.x;
    int r0 = blockIdx.x * 64;
    if (tid < 64) s_cagg[tid] = (r0 + tid < n) ? cagg[r0 + tid] : 0.0f;
    if (tid < 120) s_num[tid] = rat_num[tid];
    if (tid < 80) s_den[tid] = rat_den[tid];
    if (tid < HID) { s_cl[tid] = cl_assign[tid]; s_sum[tid] = 0.0f; s_sq[tid] = 0.0f; }
    __syncthreads();
    // A staging with BN affine: 8 float4 loads per thread
    {
        int cv = (tid & 31) * 4;
        int rr = tid >> 5;
        float4 w4 = *(const float4*)&bnw[cv];
        float4 u4 = *(const float4*)&bnu[cv];
        #pragma unroll
        for (int i = 0; i < 8; i++) {
            int r = rr + i * 8;
            int gr = r0 + r;
            float cg = s_cagg[r];
            float4 v = (gr < n) ? *(const float4*)&aggY[gr * HID + cv]
                                : make_float4(0.0f, 0.0f, 0.0f, 0.0f);
            As[(cv + 0) * 68 + r] = fmaf(w4.x, v.x, u4.x * cg);
            As[(cv + 1) * 68 + r] = fmaf(w4.y, v.y, u4.y * cg);
            As[(cv + 2) * 68 + r] = fmaf(w4.z, v.z, u4.z * cg);
            As[(cv + 3) * 68 + r] = fmaf(w4.w, v.w, u4.w * cg);
        }
    }
    int tc = (tid & 31) << 2;
    int tr = (tid >> 5) << 3;
    float acc[8][4];
    #pragma unroll
    for (int i = 0; i < 8; i++)
        #pragma unroll
        for (int j = 0; j < 4; j++) acc[i][j] = 0.0f;
    for (int kk = 0; kk < HID; kk += 32) {
        __syncthreads();
        #pragma unroll
        for (int i = 0; i < 16; i++) {
            int idx = tid + i * 256;
            int k = idx >> 7, c = idx & 127;
            Bs[k * HID + c] = W[(kk + k) * HID + c];
        }
        __syncthreads();
        #pragma unroll
        for (int k = 0; k < 32; k++) {
            const float4 b4 = *(const float4*)&Bs[k * HID + tc];
            const float4 a0 = *(const float4*)&As[(kk + k) * 68 + tr];
            const float4 a1 = *(const float4*)&As[(kk + k) * 68 + tr + 4];
            float av[8] = {a0.x, a0.y, a0.z, a0.w, a1.x, a1.y, a1.z, a1.w};
            float bv[4] = {b4.x, b4.y, b4.z, b4.w};
            #pragma unroll
            for (int i = 0; i < 8; i++)
                #pragma unroll
                for (int j = 0; j < 4; j++) acc[i][j] = fmaf(av[i], bv[j], acc[i][j]);
        }
    }
    // epilogue: bias + rational + stats + store
    float bb[4];
    const float* an[4]; const float* qd[4];
    #pragma unroll
    for (int j = 0; j < 4; j++) {
        bb[j] = bias[tc + j];
        an[j] = s_num + s_cl[tc + j] * 6;
        qd[j] = s_den + s_cl[tc + j] * 4;
    }
    float psum[4] = {0, 0, 0, 0}, psq[4] = {0, 0, 0, 0};
    #pragma unroll
    for (int i = 0; i < 8; i++) {
        int gr = r0 + tr + i;
        if (gr < n) {
            float4 o;
            float r0v = rational_act(acc[i][0] + bb[0], an[0], qd[0]);
            float r1v = rational_act(acc[i][1] + bb[1], an[1], qd[1]);
            float r2v = rational_act(acc[i][2] + bb[2], an[2], qd[2]);
            float r3v = rational_act(acc[i][3] + bb[3], an[3], qd[3]);
            o.x = r0v; o.y = r1v; o.z = r2v; o.w = r3v;
            psum[0] += r0v; psq[0] = fmaf(r0v, r0v, psq[0]);
            psum[1] += r1v; psq[1] = fmaf(r1v, r1v, psq[1]);
            psum[2] += r2v; psq[2] = fmaf(r2v, r2v, psq[2]);
            psum[3] += r3v; psq[3] = fmaf(r3v, r3v, psq[3]);
            *(float4*)&act[gr * HID + tc] = o;
        }
    }
    #pragma unroll
    for (int j = 0; j < 4; j++) {
        atomicAdd(&s_sum[tc + j], psum[j]);
        atomicAdd(&s_sq[tc + j], psq[j]);
    }
    __syncthreads();
    if (tid < HID) {
        atomicAdd(&stat[tid], s_sum[tid]);
        atomicAdd(&stat[HID + tid], s_sq[tid]);
    }
}

__global__ void bn_finalize_kernel(const float* __restrict__ stat, const float* __restrict__ g,
                                   const float* __restrict__ be, float* __restrict__ bnw,
                                   float* __restrict__ bnu, int n) {
    int c = threadIdx.x;
    float inv_n = 1.0f / (float)n;
    float mean = stat[c] * inv_n;
    float var = stat[HID + c] * inv_n - mean * mean;
    float w = g[c] * rsqrtf(var + 1e-5f);
    bnw[c] = w;
    bnu[c] = be[c] - mean * w;
}

// ---------------- pooling by graph ----------------
__global__ void pool_kernel(const float* __restrict__ act, const int* __restrict__ gstart,
                            const int* __restrict__ gend, const float* __restrict__ bnw,
                            const float* __restrict__ bnu, float* __restrict__ pooledf) {
    int g = blockIdx.x, c = threadIdx.x;
    int s = gstart[g], e = gend[g];
    float acc = 0.0f;
    for (int r = s; r < e; r++) acc += act[r * HID + c];
    int cnt = e - s;
    pooledf[g * HID + c] = (cnt > 0) ? fmaf(bnw[c], acc / (float)cnt, bnu[c]) : 0.0f;
}

// ---------------- MLP ----------------
__global__ void mlp_gelu_kernel(const float* __restrict__ in, const float* __restrict__ W,
                                const float* __restrict__ b, float* __restrict__ out) {
    __shared__ float rs[HID];
    int g = blockIdx.x, c = threadIdx.x;
    rs[c] = in[g * HID + c];
    __syncthreads();
    float acc = b[c];
    #pragma unroll 8
    for (int k = 0; k < HID; k++) acc = fmaf(rs[k], W[k * HID + c], acc);
    out[g * HID + c] = 0.5f * acc * (1.0f + erff(acc * 0.70710678118654752f));
}

__global__ void mlp_out_kernel(const float* __restrict__ in, const float* __restrict__ W,
                               const float* __restrict__ b, float* __restrict__ out) {
    __shared__ float rs[HID];
    int g = blockIdx.x, c = threadIdx.x;
    rs[c] = in[g * HID + c];
    __syncthreads();
    if (c < OUTF) {
        float acc = b[c];
        #pragma unroll 8
        for (int k = 0; k < HID; k++) acc = fmaf(rs[k], W[k * OUTF + c], acc);
        out[g * OUTF + c] = acc;
    }
}

extern "C" void kernel_launch(void* const* d_in, const int* in_sizes, int n_in,
                              void* d_out, int out_size, void* d_ws, size_t ws_size,
                              hipStream_t stream) {
    const float* x          = (const float*)d_in[0];
    const int*   edge_index = (const int*)d_in[1];
    const int*   batch      = (const int*)d_in[2];
    const float* W[4]  = {(const float*)d_in[3], (const float*)d_in[7], (const float*)d_in[11], (const float*)d_in[15]};
    const float* bL[4] = {(const float*)d_in[4], (const float*)d_in[8], (const float*)d_in[12], (const float*)d_in[16]};
    const float* gL[4] = {(const float*)d_in[5], (const float*)d_in[9], (const float*)d_in[13], (const float*)d_in[17]};
    const float* beL[4]= {(const float*)d_in[6], (const float*)d_in[10], (const float*)d_in[14], (const float*)d_in[18]};
    const float* rat_num = (const float*)d_in[19];
    const float* rat_den = (const float*)d_in[20];
    const int*   cl_assign = (const int*)d_in[21];
    const float* HW1 = (const float*)d_in[22];
    const float* Hb1 = (const float*)d_in[23];
    const float* HW2 = (const float*)d_in[24];
    const float* Hb2 = (const float*)d_in[25];
    const float* HW3 = (const float*)d_in[26];
    const float* Hb3 = (const float*)d_in[27];
    float* out = (float*)d_out;

    const int N = in_sizes[0] / INF;
    const int E = in_sizes[1] / 2;

    // ---- workspace layout ----
    char* wsb = (char*)d_ws;
    size_t o = 0;
    int*   cnt     = (int*)(wsb + o * 4);  o += N;          // zeroed; reused as cagg later
    int*   gstart  = (int*)(wsb + o * 4);  o += GRP;        // zeroed
    int*   gend    = (int*)(wsb + o * 4);  o += GRP;        // zeroed
    float* bnstat  = (float*)(wsb + o * 4); o += 4 * 256;   // zeroed
    size_t zero_elems = o;
    int*   cursor  = (int*)(wsb + o * 4);  o += N;          // init by scan
    int*   row_ptr = (int*)(wsb + o * 4);  o += N + 1;
    o = (o + 3) & ~(size_t)3;
    float* dinv    = (float*)(wsb + o * 4); o += N;
    int*   csr_src = (int*)(wsb + o * 4);   o += E;
    float* csr_coef= (float*)(wsb + o * 4); o += E;
    float* bnw     = (float*)(wsb + o * 4); o += 4 * HID;
    float* bnu     = (float*)(wsb + o * 4); o += 4 * HID;
    float* pooledf = (float*)(wsb + o * 4); o += GRP * HID;
    float* z1      = (float*)(wsb + o * 4); o += GRP * HID;
    float* z2      = (float*)(wsb + o * 4); o += GRP * HID;
    o = (o + 3) & ~(size_t)3;
    float* big0    = (float*)(wsb + o * 4); o += (size_t)N * HID;  // aggX (Nx9) then aggY (Nx128)
    float* act     = (float*)(wsb + o * 4); o += (size_t)N * HID;
    float* cagg    = (float*)cnt;   // reuse: cnt dead after scan
    float* aggX    = big0;
    float* aggY    = big0;

    hipMemsetAsync(d_ws, 0, zero_elems * 4, stream);

    int eb = (E + 255) / 256;
    hist_kernel<<<eb, 256, 0, stream>>>(edge_index, cnt, E);
    scan_kernel<<<1, 1024, 0, stream>>>(cnt, row_ptr, cursor, dinv, N);
    fill_kernel<<<eb, 256, 0, stream>>>(edge_index, cursor, dinv, csr_src, csr_coef, E);
    bounds_kernel<<<(N + 255) / 256, 256, 0, stream>>>(batch, gstart, gend, N);

    // layer 0: aggregate x (9 ch) then fused GEMM
    aggx_kernel<<<(N + 15) / 16, 256, 0, stream>>>(x, row_ptr, csr_src, csr_coef, dinv,
                                                   aggX, cagg, N);
    gemm0_fused_kernel<<<1024, 256, 0, stream>>>(aggX, W[0], bL[0], rat_num, rat_den,
                                                 cl_assign, act, bnstat, N);
    bn_finalize_kernel<<<1, HID, 0, stream>>>(bnstat, gL[0], beL[0], bnw, bnu, N);

    int agg_grid = (N + 7) / 8;
    int gemm_grid = (N + 63) / 64;
    for (int l = 1; l < 4; l++) {
        agg_kernel<<<agg_grid, 256, 0, stream>>>((const float4*)act, row_ptr, csr_src,
                                                 csr_coef, dinv, (float4*)aggY, N);
        gemm_fused_kernel<<<gemm_grid, 256, 0, stream>>>(aggY, W[l], bL[l],
                                                         bnw + (l - 1) * HID, bnu + (l - 1) * HID,
                                                         cagg, rat_num, rat_den, cl_assign,
                                                         act, bnstat + l * 256, N);
        bn_finalize_kernel<<<1, HID, 0, stream>>>(bnstat + l * 256, gL[l], beL[l],
                                                  bnw + l * HID, bnu + l * HID, N);
    }
    pool_kernel<<<GRP, HID, 0, stream>>>(act, gstart, gend, bnw + 3 * HID, bnu + 3 * HID, pooledf);
    mlp_gelu_kernel<<<GRP, HID, 0, stream>>>(pooledf, HW1, Hb1, z1);
    mlp_gelu_kernel<<<GRP, HID, 0, stream>>>(z1, HW2, Hb2, z2);
    mlp_out_kernel<<<GRP, HID, 0, stream>>>(z2, HW3, Hb3, out);
}

// Round 4
// 706.882 us; speedup vs baseline: 1.7539x; 1.1127x over previous
//
#include <hip/hip_runtime.h>
#include <math.h>

#define HID 128
#define GRP 256
#define INF 9
#define OUTF 10

typedef __attribute__((ext_vector_type(8))) short short8;   // 8 bf16
typedef __attribute__((ext_vector_type(4))) float f32x4;

__device__ __forceinline__ float bf2f(unsigned short u) {
    union { unsigned int i; float f; } v; v.i = ((unsigned int)u) << 16; return v.f;
}
__device__ __forceinline__ unsigned short f2bf(float f) {
    union { float f; unsigned int i; } v; v.f = f;
    unsigned int x = v.i;
    unsigned int r = x + 0x7fffu + ((x >> 16) & 1u);
    return (unsigned short)(r >> 16);
}

// ---------------- degree histogram over dst ----------------
__global__ void hist_kernel(const int* __restrict__ ei, int* __restrict__ cnt, int E) {
    int e = blockIdx.x * blockDim.x + threadIdx.x;
    if (e < E) atomicAdd(&cnt[ei[E + e]], 1);
}

// ---------------- single-block exclusive scan (+dinv); writes row_ptr AND cursor ----------------
__global__ __launch_bounds__(1024) void scan_kernel(const int* __restrict__ cnt,
                                                    int* __restrict__ row_ptr,
                                                    int* __restrict__ cursor,
                                                    float* __restrict__ dinv, int n) {
    __shared__ int warp_sums[16];
    __shared__ int chunk_carry;
    int tid = threadIdx.x;
    int lane = tid & 63, wid = tid >> 6;
    if (tid == 0) chunk_carry = 0;
    __syncthreads();
    for (int base = 0; base < n; base += 4096) {
        int idx0 = base + tid * 4;
        int v[4];
        #pragma unroll
        for (int i = 0; i < 4; i++) v[i] = (idx0 + i < n) ? cnt[idx0 + i] : 0;
        int s = v[0] + v[1] + v[2] + v[3];
        int ps = s;
        #pragma unroll
        for (int off = 1; off < 64; off <<= 1) {
            int t = __shfl_up(ps, off);
            if (lane >= off) ps += t;
        }
        if (lane == 63) warp_sums[wid] = ps;
        __syncthreads();
        if (wid == 0 && lane < 16) {
            int ws = warp_sums[lane];
            #pragma unroll
            for (int off = 1; off < 16; off <<= 1) {
                int t = __shfl_up(ws, off);
                if (lane >= off) ws += t;
            }
            warp_sums[lane] = ws;
        }
        __syncthreads();
        int offset = chunk_carry + (wid > 0 ? warp_sums[wid - 1] : 0) + (ps - s);
        int run = offset;
        #pragma unroll
        for (int i = 0; i < 4; i++) {
            if (idx0 + i < n) {
                row_ptr[idx0 + i] = run;
                cursor[idx0 + i] = run;
                dinv[idx0 + i] = rsqrtf((float)(v[i] + 1));
                run += v[i];
            }
        }
        __syncthreads();
        if (tid == 0) chunk_carry += warp_sums[15];
        __syncthreads();
    }
    if (tid == 0) row_ptr[n] = chunk_carry;
}

// ---------------- CSR fill ----------------
__global__ void fill_kernel(const int* __restrict__ ei, int* __restrict__ cursor,
                            const float* __restrict__ dinv,
                            int* __restrict__ csr_src, float* __restrict__ csr_coef, int E) {
    int e = blockIdx.x * blockDim.x + threadIdx.x;
    if (e >= E) return;
    int s = ei[e], d = ei[E + e];
    int pos = atomicAdd(&cursor[d], 1);
    csr_src[pos] = s;
    csr_coef[pos] = dinv[s] * dinv[d];
}

// ---------------- graph boundary detection ----------------
__global__ void bounds_kernel(const int* __restrict__ batch, int* __restrict__ gstart,
                              int* __restrict__ gend, int n) {
    int i = blockIdx.x * blockDim.x + threadIdx.x;
    if (i >= n) return;
    int b = batch[i];
    if (i == 0 || batch[i - 1] != b) gstart[b] = i;
    if (i == n - 1 || batch[i + 1] != b) gend[b] = i + 1;
}

// ---------------- W -> split bf16 hi/lo, MFMA fragment order ----------------
// Fragment layout: off = ((nt*4 + kc)*64 + quad*16 + l16)*8 + j
// where n = nt*16 + l16 (output col), k = kc*32 + quad*8 + j.
__global__ void prep_w_kernel(const float* __restrict__ W,
                              unsigned short* __restrict__ Whi,
                              unsigned short* __restrict__ Wlo) {
    int idx = blockIdx.x * blockDim.x + threadIdx.x;
    if (idx >= HID * HID) return;
    int nn = idx >> 7, k = idx & 127;
    float w = W[k * HID + nn];
    unsigned short hi = f2bf(w);
    float lo = w - bf2f(hi);
    unsigned short lo16 = f2bf(lo);
    int nt = nn >> 4, l16 = nn & 15;
    int kc = k >> 5, quad = (k >> 3) & 3, j = k & 7;
    int off = (((nt * 4 + kc) * 4 + quad) * 16 + l16) * 8 + j;
    Whi[off] = hi;
    Wlo[off] = lo16;
}

// ---------------- rational activation ----------------
__device__ __forceinline__ float rational_act(float xv, const float* __restrict__ a,
                                              const float* __restrict__ q) {
    float P = a[5];
    P = fmaf(P, xv, a[4]); P = fmaf(P, xv, a[3]); P = fmaf(P, xv, a[2]);
    P = fmaf(P, xv, a[1]); P = fmaf(P, xv, a[0]);
    float Q = q[3];
    Q = fmaf(Q, xv, q[2]); Q = fmaf(Q, xv, q[1]); Q = fmaf(Q, xv, q[0]);
    Q *= xv;
    return P / (1.0f + fabsf(Q));
}

// ---------------- aggregate x (9 channels) + cagg ----------------
__global__ __launch_bounds__(256) void aggx_kernel(const float* __restrict__ x,
                                                   const int* __restrict__ row_ptr,
                                                   const int* __restrict__ csr_src,
                                                   const float* __restrict__ csr_coef,
                                                   const float* __restrict__ dinv,
                                                   float* __restrict__ aggX,
                                                   float* __restrict__ cagg, int n) {
    int tid = threadIdx.x;
    int node = blockIdx.x * 16 + (tid >> 4);
    int lane = tid & 15;
    if (node >= n) return;
    float di = dinv[node];
    float self = di * di;
    float acc = (lane < INF) ? x[node * INF + lane] * self : 0.0f;
    float cfs = self;
    int beg = row_ptr[node], end = row_ptr[node + 1];
    for (int j = beg; j < end; j++) {
        int s = csr_src[j];
        float cf = csr_coef[j];
        cfs += cf;
        if (lane < INF) acc = fmaf(cf, x[s * INF + lane], acc);
    }
    if (lane < INF) aggX[node * INF + lane] = acc;
    if (lane == 0) cagg[node] = cfs;
}

// ---------------- layer-0: aggX(Nx9) @ W0 + b0 -> rational -> act(fp32) + stats ----------------
__global__ __launch_bounds__(256) void gemm0_fused_kernel(const float* __restrict__ aggX,
                                                          const float* __restrict__ W0,
                                                          const float* __restrict__ b0,
                                                          const float* __restrict__ rat_num,
                                                          const float* __restrict__ rat_den,
                                                          const int* __restrict__ cl_assign,
                                                          float* __restrict__ act,
                                                          float* __restrict__ stat, int n) {
    __shared__ float Ws[INF * HID];
    __shared__ float s_num[120], s_den[80];
    __shared__ int s_cl[HID];
    __shared__ float s_b[HID];
    __shared__ float s_sum[HID], s_sq[HID];
    int tid = threadIdx.x;
    for (int i = tid; i < INF * HID; i += 256) Ws[i] = W0[i];
    if (tid < 120) s_num[tid] = rat_num[tid];
    if (tid < 80) s_den[tid] = rat_den[tid];
    if (tid < HID) {
        s_cl[tid] = cl_assign[tid];
        s_b[tid] = b0[tid];
        s_sum[tid] = 0.0f; s_sq[tid] = 0.0f;
    }
    __syncthreads();
    int c = tid & 127;
    int half = tid >> 7;
    const float* a = s_num + s_cl[c] * 6;
    const float* q = s_den + s_cl[c] * 4;
    float psum = 0.0f, psq = 0.0f;
    for (int node = blockIdx.x * 2 + half; node < n; node += gridDim.x * 2) {
        float acc = s_b[c];
        #pragma unroll
        for (int k = 0; k < INF; k++) acc = fmaf(aggX[node * INF + k], Ws[k * HID + c], acc);
        float r = rational_act(acc, a, q);
        act[node * HID + c] = r;
        psum += r; psq = fmaf(r, r, psq);
    }
    atomicAdd(&s_sum[c], psum);
    atomicAdd(&s_sq[c], psq);
    __syncthreads();
    if (tid < HID) {
        atomicAdd(&stat[tid], s_sum[tid]);
        atomicAdd(&stat[HID + tid], s_sq[tid]);
    }
}

// ---------------- gather-aggregate act (fp32) + BN affine -> A hi/lo bf16 ----------------
__global__ __launch_bounds__(256) void agg_split_kernel(const float4* __restrict__ act4,
                                                        const int* __restrict__ row_ptr,
                                                        const int* __restrict__ csr_src,
                                                        const float* __restrict__ csr_coef,
                                                        const float* __restrict__ dinv,
                                                        const float* __restrict__ cagg,
                                                        const float* __restrict__ bnw,
                                                        const float* __restrict__ bnu,
                                                        ushort4* __restrict__ Ahi4,
                                                        ushort4* __restrict__ Alo4, int n) {
    __shared__ int s_src[8][32];
    __shared__ float s_cf[8][32];
    int tid = threadIdx.x;
    int row = tid >> 5, lane = tid & 31;
    int node = blockIdx.x * 8 + row;
    if (node >= n) return;
    float di = dinv[node];
    float selfc = di * di;
    float4 a = act4[node * 32 + lane];
    float4 acc;
    acc.x = a.x * selfc; acc.y = a.y * selfc; acc.z = a.z * selfc; acc.w = a.w * selfc;
    int beg = row_ptr[node], end = row_ptr[node + 1];
    for (int base = beg; base < end; base += 32) {
        int m = end - base; if (m > 32) m = 32;
        if (lane < m) {
            s_src[row][lane] = csr_src[base + lane];
            s_cf[row][lane] = csr_coef[base + lane];
        }
        __builtin_amdgcn_wave_barrier();
        int j = 0;
        for (; j + 4 <= m; j += 4) {
            int i0 = s_src[row][j], i1 = s_src[row][j + 1];
            int i2 = s_src[row][j + 2], i3 = s_src[row][j + 3];
            float c0 = s_cf[row][j], c1 = s_cf[row][j + 1];
            float c2 = s_cf[row][j + 2], c3 = s_cf[row][j + 3];
            float4 v0 = act4[i0 * 32 + lane];
            float4 v1 = act4[i1 * 32 + lane];
            float4 v2 = act4[i2 * 32 + lane];
            float4 v3 = act4[i3 * 32 + lane];
            acc.x = fmaf(c0, v0.x, acc.x); acc.y = fmaf(c0, v0.y, acc.y);
            acc.z = fmaf(c0, v0.z, acc.z); acc.w = fmaf(c0, v0.w, acc.w);
            acc.x = fmaf(c1, v1.x, acc.x); acc.y = fmaf(c1, v1.y, acc.y);
            acc.z = fmaf(c1, v1.z, acc.z); acc.w = fmaf(c1, v1.w, acc.w);
            acc.x = fmaf(c2, v2.x, acc.x); acc.y = fmaf(c2, v2.y, acc.y);
            acc.z = fmaf(c2, v2.z, acc.z); acc.w = fmaf(c2, v2.w, acc.w);
            acc.x = fmaf(c3, v3.x, acc.x); acc.y = fmaf(c3, v3.y, acc.y);
            acc.z = fmaf(c3, v3.z, acc.z); acc.w = fmaf(c3, v3.w, acc.w);
        }
        for (; j < m; j++) {
            int s = s_src[row][j];
            float cf = s_cf[row][j];
            float4 v = act4[s * 32 + lane];
            acc.x = fmaf(cf, v.x, acc.x); acc.y = fmaf(cf, v.y, acc.y);
            acc.z = fmaf(cf, v.z, acc.z); acc.w = fmaf(cf, v.w, acc.w);
        }
    }
    // BN affine of previous layer, then split to bf16 hi/lo
    float cg = cagg[node];
    float4 w4 = *(const float4*)&bnw[lane * 4];
    float4 u4 = *(const float4*)&bnu[lane * 4];
    float fx = fmaf(w4.x, acc.x, u4.x * cg);
    float fy = fmaf(w4.y, acc.y, u4.y * cg);
    float fz = fmaf(w4.z, acc.z, u4.z * cg);
    float fw = fmaf(w4.w, acc.w, u4.w * cg);
    ushort4 hi, lo;
    hi.x = f2bf(fx); lo.x = f2bf(fx - bf2f(hi.x));
    hi.y = f2bf(fy); lo.y = f2bf(fy - bf2f(hi.y));
    hi.z = f2bf(fz); lo.z = f2bf(fz - bf2f(hi.z));
    hi.w = f2bf(fw); lo.w = f2bf(fw - bf2f(hi.w));
    Ahi4[node * 32 + lane] = hi;
    Alo4[node * 32 + lane] = lo;
}

// ---------------- split-bf16 MFMA GEMM (layers 1-3) ----------------
// act = rational(A @ W + bias) fp32, + stats. 256 threads = 4 waves, 64 rows/block.
// W resident in LDS in fragment order (hi & lo); K-loop barrier-free.
__global__ __launch_bounds__(256) void gemm_mfma_kernel(const unsigned short* __restrict__ Ahi,
                                                        const unsigned short* __restrict__ Alo,
                                                        const unsigned short* __restrict__ Whi,
                                                        const unsigned short* __restrict__ Wlo,
                                                        const float* __restrict__ bias,
                                                        const float* __restrict__ rat_num,
                                                        const float* __restrict__ rat_den,
                                                        const int* __restrict__ cl_assign,
                                                        float* __restrict__ act,
                                                        float* __restrict__ stat, int n) {
    __shared__ unsigned short WldsHi[HID * HID];   // fragment order
    __shared__ unsigned short WldsLo[HID * HID];
    __shared__ float s_num[120], s_den[80];
    __shared__ int s_cl[HID];
    __shared__ float s_bias[HID];
    __shared__ float s_sum[HID], s_sq[HID];
    int tid = threadIdx.x;
    #pragma unroll
    for (int p = 0; p < 8; p++) {
        int g = p * 256 + tid;     // granule of 8 bf16
        *(short8*)&WldsHi[g * 8] = *(const short8*)&Whi[g * 8];
        *(short8*)&WldsLo[g * 8] = *(const short8*)&Wlo[g * 8];
    }
    if (tid < 120) s_num[tid] = rat_num[tid];
    if (tid < 80) s_den[tid] = rat_den[tid];
    if (tid < HID) {
        s_cl[tid] = cl_assign[tid];
        s_bias[tid] = bias[tid];
        s_sum[tid] = 0.0f; s_sq[tid] = 0.0f;
    }
    __syncthreads();

    int w = tid >> 6, lane = tid & 63;
    int quad = lane >> 4, l16 = lane & 15;
    int r0 = blockIdx.x * 64 + w * 16;

    f32x4 acc[8];
    #pragma unroll
    for (int j = 0; j < 8; j++) acc[j] = (f32x4){0.f, 0.f, 0.f, 0.f};

    int rowA = r0 + l16;
    int rcA = (rowA < n) ? rowA : 0;
    #pragma unroll
    for (int kc = 0; kc < 4; kc++) {
        short8 ah = *(const short8*)&Ahi[rcA * HID + kc * 32 + quad * 8];
        short8 al = *(const short8*)&Alo[rcA * HID + kc * 32 + quad * 8];
        #pragma unroll
        for (int nt = 0; nt < 8; nt++) {
            int boff = ((nt * 4 + kc) * 64 + lane) * 8;
            short8 bh = *(const short8*)&WldsHi[boff];
            short8 bl = *(const short8*)&WldsLo[boff];
            acc[nt] = __builtin_amdgcn_mfma_f32_16x16x32_bf16(ah, bh, acc[nt], 0, 0, 0);
            acc[nt] = __builtin_amdgcn_mfma_f32_16x16x32_bf16(ah, bl, acc[nt], 0, 0, 0);
            acc[nt] = __builtin_amdgcn_mfma_f32_16x16x32_bf16(al, bh, acc[nt], 0, 0, 0);
        }
    }

    // epilogue: bias + rational + fp32 store + stats (C layout: col=l16, row=quad*4+reg)
    float ps[8], pq[8];
    #pragma unroll
    for (int nt = 0; nt < 8; nt++) { ps[nt] = 0.0f; pq[nt] = 0.0f; }
    #pragma unroll
    for (int reg = 0; reg < 4; reg++) {
        int row = r0 + quad * 4 + reg;
        if (row < n) {
            #pragma unroll
            for (int nt = 0; nt < 8; nt++) {
                int col = nt * 16 + l16;
                float v = acc[nt][reg] + s_bias[col];
                float r = rational_act(v, s_num + s_cl[col] * 6, s_den + s_cl[col] * 4);
                act[row * HID + col] = r;
                ps[nt] += r; pq[nt] = fmaf(r, r, pq[nt]);
            }
        }
    }
    #pragma unroll
    for (int nt = 0; nt < 8; nt++) {
        int col = nt * 16 + l16;
        atomicAdd(&s_sum[col], ps[nt]);
        atomicAdd(&s_sq[col], pq[nt]);
    }
    __syncthreads();
    if (tid < HID) {
        atomicAdd(&stat[tid], s_sum[tid]);
        atomicAdd(&stat[HID + tid], s_sq[tid]);
    }
}

__global__ void bn_finalize_kernel(const float* __restrict__ stat, const float* __restrict__ g,
                                   const float* __restrict__ be, float* __restrict__ bnw,
                                   float* __restrict__ bnu, int n) {
    int c = threadIdx.x;
    float inv_n = 1.0f / (float)n;
    float mean = stat[c] * inv_n;
    float var = stat[HID + c] * inv_n - mean * mean;
    float w = g[c] * rsqrtf(var + 1e-5f);
    bnw[c] = w;
    bnu[c] = be[c] - mean * w;
}

// ---------------- pooling by graph (fp32 act, 8 row-groups parallel) ----------------
__global__ __launch_bounds__(256) void pool_kernel(const float4* __restrict__ act4,
                                                   const int* __restrict__ gstart,
                                                   const int* __restrict__ gend,
                                                   const float* __restrict__ bnw,
                                                   const float* __restrict__ bnu,
                                                   float* __restrict__ pooledf) {
    __shared__ float4 red[8][32];
    int g = blockIdx.x;
    int tid = threadIdx.x;
    int lane = tid & 31, rg = tid >> 5;
    int s = gstart[g], e = gend[g];
    float ax = 0.f, ay = 0.f, az = 0.f, aw = 0.f;
    for (int r = s + rg; r < e; r += 8) {
        float4 v = act4[r * 32 + lane];
        ax += v.x; ay += v.y; az += v.z; aw += v.w;
    }
    red[rg][lane] = make_float4(ax, ay, az, aw);
    __syncthreads();
    if (rg == 0) {
        float4 t = red[0][lane];
        #pragma unroll
        for (int i = 1; i < 8; i++) {
            float4 u = red[i][lane];
            t.x += u.x; t.y += u.y; t.z += u.z; t.w += u.w;
        }
        int cnt = e - s;
        float4 w4 = *(const float4*)&bnw[lane * 4];
        float4 u4 = *(const float4*)&bnu[lane * 4];
        float4 o;
        if (cnt > 0) {
            float inv = 1.0f / (float)cnt;
            o.x = fmaf(w4.x, t.x * inv, u4.x);
            o.y = fmaf(w4.y, t.y * inv, u4.y);
            o.z = fmaf(w4.z, t.z * inv, u4.z);
            o.w = fmaf(w4.w, t.w * inv, u4.w);
        } else {
            o = make_float4(0.f, 0.f, 0.f, 0.f);
        }
        *(float4*)&pooledf[g * HID + lane * 4] = o;
    }
}

// ---------------- MLP ----------------
__global__ void mlp_gelu_kernel(const float* __restrict__ in, const float* __restrict__ W,
                                const float* __restrict__ b, float* __restrict__ out) {
    __shared__ float rs[HID];
    int g = blockIdx.x, c = threadIdx.x;
    rs[c] = in[g * HID + c];
    __syncthreads();
    float acc = b[c];
    #pragma unroll 8
    for (int k = 0; k < HID; k++) acc = fmaf(rs[k], W[k * HID + c], acc);
    out[g * HID + c] = 0.5f * acc * (1.0f + erff(acc * 0.70710678118654752f));
}

__global__ void mlp_out_kernel(const float* __restrict__ in, const float* __restrict__ W,
                               const float* __restrict__ b, float* __restrict__ out) {
    __shared__ float rs[HID];
    int g = blockIdx.x, c = threadIdx.x;
    rs[c] = in[g * HID + c];
    __syncthreads();
    if (c < OUTF) {
        float acc = b[c];
        #pragma unroll 8
        for (int k = 0; k < HID; k++) acc = fmaf(rs[k], W[k * OUTF + c], acc);
        out[g * OUTF + c] = acc;
    }
}

extern "C" void kernel_launch(void* const* d_in, const int* in_sizes, int n_in,
                              void* d_out, int out_size, void* d_ws, size_t ws_size,
                              hipStream_t stream) {
    const float* x          = (const float*)d_in[0];
    const int*   edge_index = (const int*)d_in[1];
    const int*   batch      = (const int*)d_in[2];
    const float* W[4]  = {(const float*)d_in[3], (const float*)d_in[7], (const float*)d_in[11], (const float*)d_in[15]};
    const float* bL[4] = {(const float*)d_in[4], (const float*)d_in[8], (const float*)d_in[12], (const float*)d_in[16]};
    const float* gL[4] = {(const float*)d_in[5], (const float*)d_in[9], (const float*)d_in[13], (const float*)d_in[17]};
    const float* beL[4]= {(const float*)d_in[6], (const float*)d_in[10], (const float*)d_in[14], (const float*)d_in[18]};
    const float* rat_num = (const float*)d_in[19];
    const float* rat_den = (const float*)d_in[20];
    const int*   cl_assign = (const int*)d_in[21];
    const float* HW1 = (const float*)d_in[22];
    const float* Hb1 = (const float*)d_in[23];
    const float* HW2 = (const float*)d_in[24];
    const float* Hb2 = (const float*)d_in[25];
    const float* HW3 = (const float*)d_in[26];
    const float* Hb3 = (const float*)d_in[27];
    float* out = (float*)d_out;

    const int N = in_sizes[0] / INF;
    const int E = in_sizes[1] / 2;

    // ---- workspace layout (dword offsets, 16B-aligned blocks) ----
    char* wsb = (char*)d_ws;
    size_t o = 0;
    #define ALIGN16 o = (o + 3) & ~(size_t)3;
    int*   cnt     = (int*)(wsb + o * 4);  o += N; ALIGN16          // zeroed; reused as cagg
    int*   gstart  = (int*)(wsb + o * 4);  o += GRP;                // zeroed
    int*   gend    = (int*)(wsb + o * 4);  o += GRP;                // zeroed
    float* bnstat  = (float*)(wsb + o * 4); o += 4 * 256;           // zeroed
    size_t zero_elems = o;
    int*   cursor  = (int*)(wsb + o * 4);  o += N; ALIGN16
    int*   row_ptr = (int*)(wsb + o * 4);  o += N + 1; ALIGN16
    float* dinv    = (float*)(wsb + o * 4); o += N; ALIGN16
    int*   csr_src = (int*)(wsb + o * 4);   o += E; ALIGN16
    float* csr_coef= (float*)(wsb + o * 4); o += E; ALIGN16
    float* bnw     = (float*)(wsb + o * 4); o += 4 * HID;
    float* bnu     = (float*)(wsb + o * 4); o += 4 * HID;
    float* pooledf = (float*)(wsb + o * 4); o += GRP * HID;
    float* z1      = (float*)(wsb + o * 4); o += GRP * HID;
    float* z2      = (float*)(wsb + o * 4); o += GRP * HID;
    float* aggX    = (float*)(wsb + o * 4); o += (size_t)N * INF; ALIGN16
    unsigned short* WhiAll = (unsigned short*)(wsb + o * 4); o += 4 * HID * HID / 2; ALIGN16
    unsigned short* WloAll = (unsigned short*)(wsb + o * 4); o += 4 * HID * HID / 2; ALIGN16
    unsigned short* A_hi   = (unsigned short*)(wsb + o * 4); o += (size_t)N * HID / 2; ALIGN16
    unsigned short* A_lo   = (unsigned short*)(wsb + o * 4); o += (size_t)N * HID / 2; ALIGN16
    float* act     = (float*)(wsb + o * 4); o += (size_t)N * HID;
    float* cagg = (float*)cnt;

    hipMemsetAsync(d_ws, 0, zero_elems * 4, stream);

    int eb = (E + 255) / 256;
    hist_kernel<<<eb, 256, 0, stream>>>(edge_index, cnt, E);
    scan_kernel<<<1, 1024, 0, stream>>>(cnt, row_ptr, cursor, dinv, N);
    fill_kernel<<<eb, 256, 0, stream>>>(edge_index, cursor, dinv, csr_src, csr_coef, E);
    bounds_kernel<<<(N + 255) / 256, 256, 0, stream>>>(batch, gstart, gend, N);
    for (int l = 1; l < 4; l++)
        prep_w_kernel<<<64, 256, 0, stream>>>(W[l], WhiAll + l * HID * HID,
                                              WloAll + l * HID * HID);

    // layer 0
    aggx_kernel<<<(N + 15) / 16, 256, 0, stream>>>(x, row_ptr, csr_src, csr_coef, dinv,
                                                   aggX, cagg, N);
    gemm0_fused_kernel<<<1024, 256, 0, stream>>>(aggX, W[0], bL[0], rat_num, rat_den,
                                                 cl_assign, act, bnstat, N);
    bn_finalize_kernel<<<1, HID, 0, stream>>>(bnstat, gL[0], beL[0], bnw, bnu, N);

    int agg_grid = (N + 7) / 8;
    int gemm_grid = (N + 63) / 64;
    for (int l = 1; l < 4; l++) {
        agg_split_kernel<<<agg_grid, 256, 0, stream>>>((const float4*)act, row_ptr, csr_src,
                                                       csr_coef, dinv, cagg,
                                                       bnw + (l - 1) * HID, bnu + (l - 1) * HID,
                                                       (ushort4*)A_hi, (ushort4*)A_lo, N);
        gemm_mfma_kernel<<<gemm_grid, 256, 0, stream>>>(A_hi, A_lo,
                                                        WhiAll + l * HID * HID,
                                                        WloAll + l * HID * HID, bL[l],
                                                        rat_num, rat_den, cl_assign,
                                                        act, bnstat + l * 256, N);
        bn_finalize_kernel<<<1, HID, 0, stream>>>(bnstat + l * 256, gL[l], beL[l],
                                                  bnw + l * HID, bnu + l * HID, N);
    }
    pool_kernel<<<GRP, 256, 0, stream>>>((const float4*)act, gstart, gend,
                                         bnw + 3 * HID, bnu + 3 * HID, pooledf);
    mlp_gelu_kernel<<<GRP, HID, 0, stream>>>(pooledf, HW1, Hb1, z1);
    mlp_gelu_kernel<<<GRP, HID, 0, stream>>>(z1, HW2, Hb2, z2);
    mlp_out_kernel<<<GRP, HID, 0, stream>>>(z2, HW3, Hb3, out);
}

// Round 5
// 600.142 us; speedup vs baseline: 2.0659x; 1.1779x over previous
//
#include <hip/hip_runtime.h>
#include <math.h>

#define HID 128
#define GRP 256
#define INF 9
#define OUTF 10

typedef _Float16 half8 __attribute__((ext_vector_type(8)));
typedef __attribute__((ext_vector_type(4))) float f32x4;

// ---------------- degree histogram over dst ----------------
__global__ void hist_kernel(const int* __restrict__ ei, int* __restrict__ cnt, int E) {
    int e = blockIdx.x * blockDim.x + threadIdx.x;
    if (e < E) atomicAdd(&cnt[ei[E + e]], 1);
}

// ---------------- single-block exclusive scan (+dinv); writes row_ptr AND cursor ----------------
__global__ __launch_bounds__(1024) void scan_kernel(const int* __restrict__ cnt,
                                                    int* __restrict__ row_ptr,
                                                    int* __restrict__ cursor,
                                                    float* __restrict__ dinv, int n) {
    __shared__ int warp_sums[16];
    __shared__ int chunk_carry;
    int tid = threadIdx.x;
    int lane = tid & 63, wid = tid >> 6;
    if (tid == 0) chunk_carry = 0;
    __syncthreads();
    for (int base = 0; base < n; base += 4096) {
        int idx0 = base + tid * 4;
        int v[4];
        #pragma unroll
        for (int i = 0; i < 4; i++) v[i] = (idx0 + i < n) ? cnt[idx0 + i] : 0;
        int s = v[0] + v[1] + v[2] + v[3];
        int ps = s;
        #pragma unroll
        for (int off = 1; off < 64; off <<= 1) {
            int t = __shfl_up(ps, off);
            if (lane >= off) ps += t;
        }
        if (lane == 63) warp_sums[wid] = ps;
        __syncthreads();
        if (wid == 0 && lane < 16) {
            int ws = warp_sums[lane];
            #pragma unroll
            for (int off = 1; off < 16; off <<= 1) {
                int t = __shfl_up(ws, off);
                if (lane >= off) ws += t;
            }
            warp_sums[lane] = ws;
        }
        __syncthreads();
        int offset = chunk_carry + (wid > 0 ? warp_sums[wid - 1] : 0) + (ps - s);
        int run = offset;
        #pragma unroll
        for (int i = 0; i < 4; i++) {
            if (idx0 + i < n) {
                row_ptr[idx0 + i] = run;
                cursor[idx0 + i] = run;
                dinv[idx0 + i] = rsqrtf((float)(v[i] + 1));
                run += v[i];
            }
        }
        __syncthreads();
        if (tid == 0) chunk_carry += warp_sums[15];
        __syncthreads();
    }
    if (tid == 0) row_ptr[n] = chunk_carry;
}

// ---------------- CSR fill ----------------
__global__ void fill_kernel(const int* __restrict__ ei, int* __restrict__ cursor,
                            const float* __restrict__ dinv,
                            int* __restrict__ csr_src, float* __restrict__ csr_coef, int E) {
    int e = blockIdx.x * blockDim.x + threadIdx.x;
    if (e >= E) return;
    int s = ei[e], d = ei[E + e];
    int pos = atomicAdd(&cursor[d], 1);
    csr_src[pos] = s;
    csr_coef[pos] = dinv[s] * dinv[d];
}

// ---------------- graph boundary detection ----------------
__global__ void bounds_kernel(const int* __restrict__ batch, int* __restrict__ gstart,
                              int* __restrict__ gend, int n) {
    int i = blockIdx.x * blockDim.x + threadIdx.x;
    if (i >= n) return;
    int b = batch[i];
    if (i == 0 || batch[i - 1] != b) gstart[b] = i;
    if (i == n - 1 || batch[i + 1] != b) gend[b] = i + 1;
}

// ---------------- W -> split fp16 hi/lo, MFMA fragment order (layers 1..3) ----------------
// off = (((nt*4 + kc)*4 + quad)*16 + l16)*8 + j ;  n = nt*16+l16, k = kc*32+quad*8+j
__global__ void prep_w_kernel(const float* __restrict__ W1, const float* __restrict__ W2,
                              const float* __restrict__ W3,
                              _Float16* __restrict__ Whi, _Float16* __restrict__ Wlo) {
    int l = blockIdx.y;                 // 0,1,2 -> layers 1,2,3
    const float* W = (l == 0) ? W1 : (l == 1) ? W2 : W3;
    int idx = blockIdx.x * blockDim.x + threadIdx.x;
    if (idx >= HID * HID) return;
    int nn = idx >> 7, k = idx & 127;
    float w = W[k * HID + nn];
    _Float16 hi = (_Float16)w;
    _Float16 lo = (_Float16)(w - (float)hi);
    int nt = nn >> 4, l16 = nn & 15;
    int kc = k >> 5, quad = (k >> 3) & 3, j = k & 7;
    size_t off = (size_t)(l + 1) * HID * HID + (((nt * 4 + kc) * 4 + quad) * 16 + l16) * 8 + j;
    Whi[off] = hi;
    Wlo[off] = lo;
}

// ---------------- rational activation ----------------
__device__ __forceinline__ float rational_act(float xv, const float* __restrict__ a,
                                              const float* __restrict__ q) {
    float P = a[5];
    P = fmaf(P, xv, a[4]); P = fmaf(P, xv, a[3]); P = fmaf(P, xv, a[2]);
    P = fmaf(P, xv, a[1]); P = fmaf(P, xv, a[0]);
    float Q = q[3];
    Q = fmaf(Q, xv, q[2]); Q = fmaf(Q, xv, q[1]); Q = fmaf(Q, xv, q[0]);
    Q *= xv;
    return P / (1.0f + fabsf(Q));
}

// ---------------- aggregate x (9 channels) + cagg ----------------
__global__ __launch_bounds__(256) void aggx_kernel(const float* __restrict__ x,
                                                   const int* __restrict__ row_ptr,
                                                   const int* __restrict__ csr_src,
                                                   const float* __restrict__ csr_coef,
                                                   const float* __restrict__ dinv,
                                                   float* __restrict__ aggX,
                                                   float* __restrict__ cagg, int n) {
    int tid = threadIdx.x;
    int node = blockIdx.x * 16 + (tid >> 4);
    int lane = tid & 15;
    if (node >= n) return;
    float di = dinv[node];
    float self = di * di;
    float acc = (lane < INF) ? x[node * INF + lane] * self : 0.0f;
    float cfs = self;
    int beg = row_ptr[node], end = row_ptr[node + 1];
    for (int j = beg; j < end; j++) {
        int s = csr_src[j];
        float cf = csr_coef[j];
        cfs += cf;
        if (lane < INF) acc = fmaf(cf, x[s * INF + lane], acc);
    }
    if (lane < INF) aggX[node * INF + lane] = acc;
    if (lane == 0) cagg[node] = cfs;
}

// ---------------- layer-0: aggX(Nx9) @ W0 + b0 -> rational -> act(fp16) + stats ----------------
__global__ __launch_bounds__(256) void gemm0_fused_kernel(const float* __restrict__ aggX,
                                                          const float* __restrict__ W0,
                                                          const float* __restrict__ b0,
                                                          const float* __restrict__ rat_num,
                                                          const float* __restrict__ rat_den,
                                                          const int* __restrict__ cl_assign,
                                                          _Float16* __restrict__ act,
                                                          float* __restrict__ stat, int n) {
    __shared__ float Ws[INF * HID];
    __shared__ float s_num[120], s_den[80];
    __shared__ int s_cl[HID];
    __shared__ float s_b[HID];
    __shared__ float s_sum[HID], s_sq[HID];
    int tid = threadIdx.x;
    for (int i = tid; i < INF * HID; i += 256) Ws[i] = W0[i];
    if (tid < 120) s_num[tid] = rat_num[tid];
    if (tid < 80) s_den[tid] = rat_den[tid];
    if (tid < HID) {
        s_cl[tid] = cl_assign[tid];
        s_b[tid] = b0[tid];
        s_sum[tid] = 0.0f; s_sq[tid] = 0.0f;
    }
    __syncthreads();
    int c = tid & 127;
    int half = tid >> 7;
    const float* a = s_num + s_cl[c] * 6;
    const float* q = s_den + s_cl[c] * 4;
    float psum = 0.0f, psq = 0.0f;
    for (int node = blockIdx.x * 2 + half; node < n; node += gridDim.x * 2) {
        float acc = s_b[c];
        #pragma unroll
        for (int k = 0; k < INF; k++) acc = fmaf(aggX[node * INF + k], Ws[k * HID + c], acc);
        float r = rational_act(acc, a, q);
        act[node * HID + c] = (_Float16)r;
        psum += r; psq = fmaf(r, r, psq);
    }
    atomicAdd(&s_sum[c], psum);
    atomicAdd(&s_sq[c], psq);
    __syncthreads();
    if (tid < HID) {
        atomicAdd(&stat[tid], s_sum[tid]);
        atomicAdd(&stat[HID + tid], s_sq[tid]);
    }
}

// ---------------- gather-aggregate act (fp16) + inline BN affine -> A (fp16) ----------------
// 16 nodes/block x 16 lanes; lane handles 8 channels (one 16B half8).
__global__ __launch_bounds__(256) void agg_kernel(const _Float16* __restrict__ act,
                                                  const int* __restrict__ row_ptr,
                                                  const int* __restrict__ csr_src,
                                                  const float* __restrict__ csr_coef,
                                                  const float* __restrict__ dinv,
                                                  const float* __restrict__ cagg,
                                                  const float* __restrict__ stat,
                                                  const float* __restrict__ g,
                                                  const float* __restrict__ be,
                                                  _Float16* __restrict__ A, int n) {
    __shared__ float s_bnw[HID], s_bnu[HID];
    __shared__ int s_src[16][16];
    __shared__ float s_cf[16][16];
    int tid = threadIdx.x;
    if (tid < HID) {
        float inv_n = 1.0f / (float)n;
        float mean = stat[tid] * inv_n;
        float var = stat[HID + tid] * inv_n - mean * mean;
        float w = g[tid] * rsqrtf(var + 1e-5f);
        s_bnw[tid] = w;
        s_bnu[tid] = be[tid] - mean * w;
    }
    __syncthreads();
    int row = tid >> 4, lane = tid & 15;
    int node = blockIdx.x * 16 + row;
    if (node >= n) return;
    const half8* act8 = (const half8*)act;
    float di = dinv[node];
    float selfc = di * di;
    half8 sv = act8[node * 16 + lane];
    float acc[8];
    #pragma unroll
    for (int t = 0; t < 8; t++) acc[t] = (float)sv[t] * selfc;
    int beg = row_ptr[node], end = row_ptr[node + 1];
    for (int base = beg; base < end; base += 16) {
        int m = end - base; if (m > 16) m = 16;
        if (lane < m) {
            s_src[row][lane] = csr_src[base + lane];
            s_cf[row][lane] = csr_coef[base + lane];
        }
        __builtin_amdgcn_wave_barrier();
        int j = 0;
        for (; j + 4 <= m; j += 4) {
            int i0 = s_src[row][j],     i1 = s_src[row][j + 1];
            int i2 = s_src[row][j + 2], i3 = s_src[row][j + 3];
            float c0 = s_cf[row][j],     c1 = s_cf[row][j + 1];
            float c2 = s_cf[row][j + 2], c3 = s_cf[row][j + 3];
            half8 v0 = act8[i0 * 16 + lane];
            half8 v1 = act8[i1 * 16 + lane];
            half8 v2 = act8[i2 * 16 + lane];
            half8 v3 = act8[i3 * 16 + lane];
            #pragma unroll
            for (int t = 0; t < 8; t++) {
                acc[t] = fmaf(c0, (float)v0[t], acc[t]);
                acc[t] = fmaf(c1, (float)v1[t], acc[t]);
                acc[t] = fmaf(c2, (float)v2[t], acc[t]);
                acc[t] = fmaf(c3, (float)v3[t], acc[t]);
            }
        }
        for (; j < m; j++) {
            int s = s_src[row][j];
            float cf = s_cf[row][j];
            half8 v = act8[s * 16 + lane];
            #pragma unroll
            for (int t = 0; t < 8; t++) acc[t] = fmaf(cf, (float)v[t], acc[t]);
        }
        __builtin_amdgcn_wave_barrier();
    }
    float cg = cagg[node];
    half8 o;
    #pragma unroll
    for (int t = 0; t < 8; t++) {
        int c = lane * 8 + t;
        o[t] = (_Float16)fmaf(s_bnw[c], acc[t], s_bnu[c] * cg);
    }
    ((half8*)A)[node * 16 + lane] = o;
}

// ---------------- fp16 MFMA GEMM (layers 1-3): act = rational(A @ W + bias) fp16, + stats ----------------
// 256 threads = 4 waves x 16 rows; W hi/lo fragments read directly from global (L1/L2-hot).
__global__ __launch_bounds__(256) void gemm_mfma_kernel(const _Float16* __restrict__ A,
                                                        const _Float16* __restrict__ Whi,
                                                        const _Float16* __restrict__ Wlo,
                                                        const float* __restrict__ bias,
                                                        const float* __restrict__ rat_num,
                                                        const float* __restrict__ rat_den,
                                                        const int* __restrict__ cl_assign,
                                                        _Float16* __restrict__ act,
                                                        float* __restrict__ stat, int n) {
    __shared__ float s_num[120], s_den[80];
    __shared__ int s_cl[HID];
    __shared__ float s_bias[HID];
    __shared__ float s_sum[HID], s_sq[HID];
    int tid = threadIdx.x;
    if (tid < 120) s_num[tid] = rat_num[tid];
    if (tid < 80) s_den[tid] = rat_den[tid];
    if (tid < HID) {
        s_cl[tid] = cl_assign[tid];
        s_bias[tid] = bias[tid];
        s_sum[tid] = 0.0f; s_sq[tid] = 0.0f;
    }
    __syncthreads();

    int w = tid >> 6, lane = tid & 63;
    int quad = lane >> 4, l16 = lane & 15;
    int r0 = blockIdx.x * 64 + w * 16;

    const half8* A8 = (const half8*)A;
    const half8* Bh8 = (const half8*)Whi;
    const half8* Bl8 = (const half8*)Wlo;

    f32x4 acc[8];
    #pragma unroll
    for (int j = 0; j < 8; j++) acc[j] = (f32x4){0.f, 0.f, 0.f, 0.f};

    int rowA = r0 + l16;
    int rcA = (rowA < n) ? rowA : 0;
    #pragma unroll
    for (int kc = 0; kc < 4; kc++) {
        half8 a = A8[rcA * 16 + kc * 4 + quad];
        #pragma unroll
        for (int nt = 0; nt < 8; nt++) {
            half8 bh = Bh8[(nt * 4 + kc) * 64 + lane];
            half8 bl = Bl8[(nt * 4 + kc) * 64 + lane];
            acc[nt] = __builtin_amdgcn_mfma_f32_16x16x32_f16(a, bh, acc[nt], 0, 0, 0);
            acc[nt] = __builtin_amdgcn_mfma_f32_16x16x32_f16(a, bl, acc[nt], 0, 0, 0);
        }
    }

    // epilogue: bias + rational + fp16 store + stats (C layout: col=l16, row=quad*4+reg)
    float ps[8], pq[8];
    #pragma unroll
    for (int nt = 0; nt < 8; nt++) { ps[nt] = 0.0f; pq[nt] = 0.0f; }
    #pragma unroll
    for (int reg = 0; reg < 4; reg++) {
        int row = r0 + quad * 4 + reg;
        if (row < n) {
            #pragma unroll
            for (int nt = 0; nt < 8; nt++) {
                int col = nt * 16 + l16;
                float v = acc[nt][reg] + s_bias[col];
                float r = rational_act(v, s_num + s_cl[col] * 6, s_den + s_cl[col] * 4);
                act[row * HID + col] = (_Float16)r;
                ps[nt] += r; pq[nt] = fmaf(r, r, pq[nt]);
            }
        }
    }
    #pragma unroll
    for (int nt = 0; nt < 8; nt++) {
        int col = nt * 16 + l16;
        atomicAdd(&s_sum[col], ps[nt]);
        atomicAdd(&s_sq[col], pq[nt]);
    }
    __syncthreads();
    if (tid < HID) {
        atomicAdd(&stat[tid], s_sum[tid]);
        atomicAdd(&stat[HID + tid], s_sq[tid]);
    }
}

// ---------------- fused pool (+final BN affine from stats) + 3-stage MLP ----------------
__global__ __launch_bounds__(256) void poolmlp_kernel(const _Float16* __restrict__ act,
                                                      const int* __restrict__ gstart,
                                                      const int* __restrict__ gend,
                                                      const float* __restrict__ stat,
                                                      const float* __restrict__ g3,
                                                      const float* __restrict__ be3,
                                                      const float* __restrict__ HW1,
                                                      const float* __restrict__ Hb1,
                                                      const float* __restrict__ HW2,
                                                      const float* __restrict__ Hb2,
                                                      const float* __restrict__ HW3,
                                                      const float* __restrict__ Hb3,
                                                      float* __restrict__ out, int n) {
    __shared__ float red[16][HID];
    __shared__ float s_pool[HID];
    __shared__ float s_z[HID];
    int gi = blockIdx.x;
    int tid = threadIdx.x;
    int rg = tid >> 4, lane = tid & 15;
    int s = gstart[gi], e = gend[gi];
    const half8* act8 = (const half8*)act;
    float a[8];
    #pragma unroll
    for (int t = 0; t < 8; t++) a[t] = 0.0f;
    for (int r = s + rg; r < e; r += 16) {
        half8 v = act8[r * 16 + lane];
        #pragma unroll
        for (int t = 0; t < 8; t++) a[t] += (float)v[t];
    }
    #pragma unroll
    for (int t = 0; t < 8; t++) red[rg][lane * 8 + t] = a[t];
    __syncthreads();
    if (tid < HID) {
        float tot = 0.0f;
        #pragma unroll
        for (int i = 0; i < 16; i++) tot += red[i][tid];
        int cnt = e - s;
        float pooled = 0.0f;
        if (cnt > 0) {
            float inv_n = 1.0f / (float)n;
            float mean = stat[tid] * inv_n;
            float var = stat[HID + tid] * inv_n - mean * mean;
            float w = g3[tid] * rsqrtf(var + 1e-5f);
            float u = be3[tid] - mean * w;
            pooled = fmaf(w, tot / (float)cnt, u);
        }
        s_pool[tid] = pooled;
    }
    __syncthreads();
    if (tid < HID) {
        float acc = Hb1[tid];
        #pragma unroll 8
        for (int k = 0; k < HID; k++) acc = fmaf(s_pool[k], HW1[k * HID + tid], acc);
        s_z[tid] = 0.5f * acc * (1.0f + erff(acc * 0.70710678118654752f));
    }
    __syncthreads();
    if (tid < HID) {
        float acc = Hb2[tid];
        #pragma unroll 8
        for (int k = 0; k < HID; k++) acc = fmaf(s_z[k], HW2[k * HID + tid], acc);
        s_pool[tid] = 0.5f * acc * (1.0f + erff(acc * 0.70710678118654752f));
    }
    __syncthreads();
    if (tid < OUTF) {
        float acc = Hb3[tid];
        #pragma unroll 8
        for (int k = 0; k < HID; k++) acc = fmaf(s_pool[k], HW3[k * OUTF + tid], acc);
        out[gi * OUTF + tid] = acc;
    }
}

extern "C" void kernel_launch(void* const* d_in, const int* in_sizes, int n_in,
                              void* d_out, int out_size, void* d_ws, size_t ws_size,
                              hipStream_t stream) {
    const float* x          = (const float*)d_in[0];
    const int*   edge_index = (const int*)d_in[1];
    const int*   batch      = (const int*)d_in[2];
    const float* W[4]  = {(const float*)d_in[3], (const float*)d_in[7], (const float*)d_in[11], (const float*)d_in[15]};
    const float* bL[4] = {(const float*)d_in[4], (const float*)d_in[8], (const float*)d_in[12], (const float*)d_in[16]};
    const float* gL[4] = {(const float*)d_in[5], (const float*)d_in[9], (const float*)d_in[13], (const float*)d_in[17]};
    const float* beL[4]= {(const float*)d_in[6], (const float*)d_in[10], (const float*)d_in[14], (const float*)d_in[18]};
    const float* rat_num = (const float*)d_in[19];
    const float* rat_den = (const float*)d_in[20];
    const int*   cl_assign = (const int*)d_in[21];
    const float* HW1 = (const float*)d_in[22];
    const float* Hb1 = (const float*)d_in[23];
    const float* HW2 = (const float*)d_in[24];
    const float* Hb2 = (const float*)d_in[25];
    const float* HW3 = (const float*)d_in[26];
    const float* Hb3 = (const float*)d_in[27];
    float* out = (float*)d_out;

    const int N = in_sizes[0] / INF;
    const int E = in_sizes[1] / 2;

    // ---- workspace layout (dword offsets; 16B alignment kept per segment) ----
    char* wsb = (char*)d_ws;
    size_t o = 0;
    #define ALIGN16 o = (o + 3) & ~(size_t)3;
    int*   cnt     = (int*)(wsb + o * 4);  o += N; ALIGN16          // zeroed; reused as cagg
    int*   gstart  = (int*)(wsb + o * 4);  o += GRP;                // zeroed
    int*   gend    = (int*)(wsb + o * 4);  o += GRP;                // zeroed
    float* bnstat  = (float*)(wsb + o * 4); o += 4 * 256;           // zeroed
    size_t zero_elems = o;
    int*   cursor  = (int*)(wsb + o * 4);  o += N; ALIGN16
    int*   row_ptr = (int*)(wsb + o * 4);  o += N + 1; ALIGN16
    float* dinv    = (float*)(wsb + o * 4); o += N; ALIGN16
    int*   csr_src = (int*)(wsb + o * 4);   o += E; ALIGN16
    float* csr_coef= (float*)(wsb + o * 4); o += E; ALIGN16
    float* aggX    = (float*)(wsb + o * 4); o += (size_t)N * INF; ALIGN16
    _Float16* WhiAll = (_Float16*)(wsb + o * 4); o += 4 * HID * HID / 2; ALIGN16
    _Float16* WloAll = (_Float16*)(wsb + o * 4); o += 4 * HID * HID / 2; ALIGN16
    _Float16* A_h    = (_Float16*)(wsb + o * 4); o += (size_t)N * HID / 2; ALIGN16
    _Float16* act_h  = (_Float16*)(wsb + o * 4); o += (size_t)N * HID / 2;
    float* cagg = (float*)cnt;

    hipMemsetAsync(d_ws, 0, zero_elems * 4, stream);

    int eb = (E + 255) / 256;
    hist_kernel<<<eb, 256, 0, stream>>>(edge_index, cnt, E);
    scan_kernel<<<1, 1024, 0, stream>>>(cnt, row_ptr, cursor, dinv, N);
    fill_kernel<<<eb, 256, 0, stream>>>(edge_index, cursor, dinv, csr_src, csr_coef, E);
    bounds_kernel<<<(N + 255) / 256, 256, 0, stream>>>(batch, gstart, gend, N);
    prep_w_kernel<<<dim3(64, 3), 256, 0, stream>>>(W[1], W[2], W[3], WhiAll, WloAll);

    // layer 0
    aggx_kernel<<<(N + 15) / 16, 256, 0, stream>>>(x, row_ptr, csr_src, csr_coef, dinv,
                                                   aggX, cagg, N);
    gemm0_fused_kernel<<<1024, 256, 0, stream>>>(aggX, W[0], bL[0], rat_num, rat_den,
                                                 cl_assign, act_h, bnstat, N);

    int agg_grid = (N + 15) / 16;
    int gemm_grid = (N + 63) / 64;
    for (int l = 1; l < 4; l++) {
        agg_kernel<<<agg_grid, 256, 0, stream>>>(act_h, row_ptr, csr_src, csr_coef, dinv,
                                                 cagg, bnstat + (l - 1) * 256,
                                                 gL[l - 1], beL[l - 1], A_h, N);
        gemm_mfma_kernel<<<gemm_grid, 256, 0, stream>>>(A_h,
                                                        WhiAll + (size_t)l * HID * HID,
                                                        WloAll + (size_t)l * HID * HID, bL[l],
                                                        rat_num, rat_den, cl_assign,
                                                        act_h, bnstat + l * 256, N);
    }
    poolmlp_kernel<<<GRP, 256, 0, stream>>>(act_h, gstart, gend, bnstat + 3 * 256,
                                            gL[3], beL[3], HW1, Hb1, HW2, Hb2, HW3, Hb3,
                                            out, N);
}

// Round 6
// 516.123 us; speedup vs baseline: 2.4022x; 1.1628x over previous
//
#include <hip/hip_runtime.h>
#include <math.h>

#define HID 128
#define GRP 256
#define INF 9
#define OUTF 10

typedef _Float16 half8 __attribute__((ext_vector_type(8)));
typedef __attribute__((ext_vector_type(4))) float f32x4;

// ---------------- histogram over dst + fold in W-prep (layers 1..3) ----------------
// W fragment order: off = (((nt*4+kc)*4+quad)*16 + l16)*8 + j ; n=nt*16+l16, k=kc*32+quad*8+j
__global__ void hist_prepw_kernel(const int* __restrict__ ei, int* __restrict__ cnt, int E,
                                  const float* __restrict__ W1, const float* __restrict__ W2,
                                  const float* __restrict__ W3,
                                  _Float16* __restrict__ Whi, _Float16* __restrict__ Wlo) {
    int e = blockIdx.x * 256 + threadIdx.x;
    if (e < E) atomicAdd(&cnt[ei[E + e]], 1);
    if (blockIdx.x < 192) {
        int l = blockIdx.x >> 6;                       // 0..2 -> layers 1..3
        int idx = (blockIdx.x & 63) * 256 + threadIdx.x;   // 0..16383
        const float* W = (l == 0) ? W1 : (l == 1) ? W2 : W3;
        int nn = idx >> 7, k = idx & 127;
        float w = W[k * HID + nn];
        _Float16 hi = (_Float16)w;
        _Float16 lo = (_Float16)(w - (float)hi);
        int nt = nn >> 4, l16 = nn & 15;
        int kc = k >> 5, quad = (k >> 3) & 3, j = k & 7;
        size_t off = (size_t)(l + 1) * HID * HID +
                     ((((nt * 4 + kc) * 4 + quad) * 16 + l16) * 8 + j);
        Whi[off] = hi;
        Wlo[off] = lo;
    }
}

// ---------------- parallel scan phase A: per-1024-chunk sums ----------------
__global__ __launch_bounds__(256) void scanA_kernel(const int* __restrict__ cnt,
                                                    int* __restrict__ bsum, int n) {
    int tid = threadIdx.x;
    int base = blockIdx.x * 1024 + tid * 4;
    int s = 0;
    #pragma unroll
    for (int i = 0; i < 4; i++) s += (base + i < n) ? cnt[base + i] : 0;
    #pragma unroll
    for (int off = 32; off > 0; off >>= 1) s += __shfl_down(s, off);
    __shared__ int ws[4];
    if ((tid & 63) == 0) ws[tid >> 6] = s;
    __syncthreads();
    if (tid == 0) bsum[blockIdx.x] = ws[0] + ws[1] + ws[2] + ws[3];
}

// ---------------- phase B: exclusive scan of block sums (in place) ----------------
__global__ void scanB_kernel(int* __restrict__ bsum, int* __restrict__ row_ptr,
                             int nb, int n) {
    int lane = threadIdx.x;   // 64 threads
    int carry = 0;
    for (int base = 0; base < nb; base += 64) {
        int v = (base + lane < nb) ? bsum[base + lane] : 0;
        int ps = v;
        #pragma unroll
        for (int off = 1; off < 64; off <<= 1) {
            int t = __shfl_up(ps, off);
            if (lane >= off) ps += t;
        }
        if (base + lane < nb) bsum[base + lane] = carry + ps - v;
        carry += __shfl(ps, 63);
    }
    if (lane == 0) row_ptr[n] = carry;
}

// ---------------- phase C: local scan + row_ptr/cursor/dinv + graph bounds ----------------
__global__ __launch_bounds__(256) void scanC_kernel(const int* __restrict__ cnt,
                                                    const int* __restrict__ bsum,
                                                    const int* __restrict__ batch,
                                                    int* __restrict__ row_ptr,
                                                    int* __restrict__ cursor,
                                                    float* __restrict__ dinv,
                                                    int* __restrict__ gstart,
                                                    int* __restrict__ gend, int n) {
    int tid = threadIdx.x;
    int lane = tid & 63, wid = tid >> 6;
    int idx0 = blockIdx.x * 1024 + tid * 4;
    int v[4];
    #pragma unroll
    for (int i = 0; i < 4; i++) v[i] = (idx0 + i < n) ? cnt[idx0 + i] : 0;
    int s = v[0] + v[1] + v[2] + v[3];
    int ps = s;
    #pragma unroll
    for (int off = 1; off < 64; off <<= 1) {
        int t = __shfl_up(ps, off);
        if (lane >= off) ps += t;
    }
    __shared__ int wsum[4];
    if (lane == 63) wsum[wid] = ps;
    __syncthreads();
    int woff = 0;
    #pragma unroll
    for (int i = 0; i < 4; i++) if (i < wid) woff += wsum[i];
    int run = bsum[blockIdx.x] + woff + (ps - s);
    #pragma unroll
    for (int i = 0; i < 4; i++) {
        int idx = idx0 + i;
        if (idx < n) {
            row_ptr[idx] = run;
            cursor[idx] = run;
            dinv[idx] = rsqrtf((float)(v[i] + 1));
            run += v[i];
            int b = batch[idx];
            if (idx == 0 || batch[idx - 1] != b) gstart[b] = idx;
            if (idx == n - 1 || batch[idx + 1] != b) gend[b] = idx + 1;
        }
    }
}

// ---------------- CSR fill: (src, coef) packed as int2, one 8B scatter ----------------
__global__ void fill_kernel(const int* __restrict__ ei, int* __restrict__ cursor,
                            const float* __restrict__ dinv,
                            int2* __restrict__ csr, int E) {
    int e = blockIdx.x * blockDim.x + threadIdx.x;
    if (e >= E) return;
    int s = ei[e], d = ei[E + e];
    int pos = atomicAdd(&cursor[d], 1);
    csr[pos] = make_int2(s, __float_as_int(dinv[s] * dinv[d]));
}

// ---------------- rational activation ----------------
__device__ __forceinline__ float rational_act(float xv, const float* __restrict__ a,
                                              const float* __restrict__ q) {
    float P = a[5];
    P = fmaf(P, xv, a[4]); P = fmaf(P, xv, a[3]); P = fmaf(P, xv, a[2]);
    P = fmaf(P, xv, a[1]); P = fmaf(P, xv, a[0]);
    float Q = q[3];
    Q = fmaf(Q, xv, q[2]); Q = fmaf(Q, xv, q[1]); Q = fmaf(Q, xv, q[0]);
    Q *= xv;
    return P / (1.0f + fabsf(Q));
}

// ---------------- aggregate x (9 channels) + cagg ----------------
__global__ __launch_bounds__(256) void aggx_kernel(const float* __restrict__ x,
                                                   const int* __restrict__ row_ptr,
                                                   const int2* __restrict__ csr,
                                                   const float* __restrict__ dinv,
                                                   float* __restrict__ aggX,
                                                   float* __restrict__ cagg, int n) {
    int tid = threadIdx.x;
    int node = blockIdx.x * 16 + (tid >> 4);
    int lane = tid & 15;
    if (node >= n) return;
    float di = dinv[node];
    float self = di * di;
    float acc = (lane < INF) ? x[node * INF + lane] * self : 0.0f;
    float cfs = self;
    int beg = row_ptr[node], end = row_ptr[node + 1];
    for (int j = beg; j < end; j++) {
        int2 p = csr[j];
        float cf = __int_as_float(p.y);
        cfs += cf;
        if (lane < INF) acc = fmaf(cf, x[p.x * INF + lane], acc);
    }
    if (lane < INF) aggX[node * INF + lane] = acc;
    if (lane == 0) cagg[node] = cfs;
}

// ---------------- layer-0: aggX(Nx9) @ W0 + b0 -> rational -> act(fp16) + stats ----------------
__global__ __launch_bounds__(256) void gemm0_fused_kernel(const float* __restrict__ aggX,
                                                          const float* __restrict__ W0,
                                                          const float* __restrict__ b0,
                                                          const float* __restrict__ rat_num,
                                                          const float* __restrict__ rat_den,
                                                          const int* __restrict__ cl_assign,
                                                          _Float16* __restrict__ act,
                                                          float* __restrict__ stat, int n) {
    __shared__ float Ws[INF * HID];
    __shared__ float s_num[120], s_den[80];
    __shared__ int s_cl[HID];
    __shared__ float s_b[HID];
    __shared__ float s_sum[HID], s_sq[HID];
    int tid = threadIdx.x;
    for (int i = tid; i < INF * HID; i += 256) Ws[i] = W0[i];
    if (tid < 120) s_num[tid] = rat_num[tid];
    if (tid < 80) s_den[tid] = rat_den[tid];
    if (tid < HID) {
        s_cl[tid] = cl_assign[tid];
        s_b[tid] = b0[tid];
        s_sum[tid] = 0.0f; s_sq[tid] = 0.0f;
    }
    __syncthreads();
    int c = tid & 127;
    int half = tid >> 7;
    const float* a = s_num + s_cl[c] * 6;
    const float* q = s_den + s_cl[c] * 4;
    float psum = 0.0f, psq = 0.0f;
    for (int node = blockIdx.x * 2 + half; node < n; node += gridDim.x * 2) {
        float acc = s_b[c];
        #pragma unroll
        for (int k = 0; k < INF; k++) acc = fmaf(aggX[node * INF + k], Ws[k * HID + c], acc);
        float r = rational_act(acc, a, q);
        act[node * HID + c] = (_Float16)r;
        psum += r; psq = fmaf(r, r, psq);
    }
    atomicAdd(&s_sum[c], psum);
    atomicAdd(&s_sq[c], psq);
    __syncthreads();
    if (tid < HID) {
        atomicAdd(&stat[tid], s_sum[tid]);
        atomicAdd(&stat[HID + tid], s_sq[tid]);
    }
}

// ---------------- fused layer (1-3): gather-agg -> LDS A-tile -> fp16 MFMA -> rational ----------------
// 256 threads; 64 rows/block. Gather: 16 groups x 16 lanes, 4 nodes each.
// A-tile in LDS fp16, row stride 136 halves (2-way bank aliasing only).
__global__ __launch_bounds__(256) void layer_fused_kernel(const _Float16* __restrict__ act,
                                                          const int2* __restrict__ csr,
                                                          const int* __restrict__ row_ptr,
                                                          const float* __restrict__ dinv,
                                                          const float* __restrict__ cagg,
                                                          const float* __restrict__ statPrev,
                                                          const float* __restrict__ gPrev,
                                                          const float* __restrict__ bePrev,
                                                          const _Float16* __restrict__ Whi,
                                                          const _Float16* __restrict__ Wlo,
                                                          const float* __restrict__ bias,
                                                          const float* __restrict__ rat_num,
                                                          const float* __restrict__ rat_den,
                                                          const int* __restrict__ cl_assign,
                                                          _Float16* __restrict__ actOut,
                                                          float* __restrict__ statOut, int n) {
    __shared__ _Float16 Alds[64 * 136];
    __shared__ int2 s_pair[16][16];
    __shared__ float s_bnw[HID], s_bnu[HID];
    __shared__ float s_num[120], s_den[80];
    __shared__ int s_cl[HID];
    __shared__ float s_bias[HID];
    __shared__ float s_sum[HID], s_sq[HID];
    int tid = threadIdx.x;
    if (tid < 120) s_num[tid] = rat_num[tid];
    if (tid < 80) s_den[tid] = rat_den[tid];
    if (tid < HID) {
        float inv_n = 1.0f / (float)n;
        float mean = statPrev[tid] * inv_n;
        float var = statPrev[HID + tid] * inv_n - mean * mean;
        float w = gPrev[tid] * rsqrtf(var + 1e-5f);
        s_bnw[tid] = w;
        s_bnu[tid] = bePrev[tid] - mean * w;
        s_cl[tid] = cl_assign[tid];
        s_bias[tid] = bias[tid];
        s_sum[tid] = 0.0f; s_sq[tid] = 0.0f;
    }
    __syncthreads();

    int r0 = blockIdx.x * 64;
    int grp = tid >> 4, glane = tid & 15;
    const half8* act8 = (const half8*)act;

    // ---- gather phase: 4 nodes per 16-lane group ----
    for (int sub = 0; sub < 4; sub++) {
        int lrow = sub * 16 + grp;
        int node = r0 + lrow;
        half8 o;
        if (node < n) {
            float di = dinv[node];
            float selfc = di * di;
            half8 sv = act8[node * 16 + glane];
            float acc[8];
            #pragma unroll
            for (int t = 0; t < 8; t++) acc[t] = (float)sv[t] * selfc;
            int beg = row_ptr[node], end = row_ptr[node + 1];
            for (int base = beg; base < end; base += 16) {
                int m = end - base; if (m > 16) m = 16;
                if (glane < m) s_pair[grp][glane] = csr[base + glane];
                __builtin_amdgcn_wave_barrier();
                int j = 0;
                for (; j + 4 <= m; j += 4) {
                    int2 p0 = s_pair[grp][j],     p1 = s_pair[grp][j + 1];
                    int2 p2 = s_pair[grp][j + 2], p3 = s_pair[grp][j + 3];
                    half8 v0 = act8[p0.x * 16 + glane];
                    half8 v1 = act8[p1.x * 16 + glane];
                    half8 v2 = act8[p2.x * 16 + glane];
                    half8 v3 = act8[p3.x * 16 + glane];
                    float c0 = __int_as_float(p0.y), c1 = __int_as_float(p1.y);
                    float c2 = __int_as_float(p2.y), c3 = __int_as_float(p3.y);
                    #pragma unroll
                    for (int t = 0; t < 8; t++) {
                        acc[t] = fmaf(c0, (float)v0[t], acc[t]);
                        acc[t] = fmaf(c1, (float)v1[t], acc[t]);
                        acc[t] = fmaf(c2, (float)v2[t], acc[t]);
                        acc[t] = fmaf(c3, (float)v3[t], acc[t]);
                    }
                }
                for (; j < m; j++) {
                    int2 p = s_pair[grp][j];
                    float cf = __int_as_float(p.y);
                    half8 v = act8[p.x * 16 + glane];
                    #pragma unroll
                    for (int t = 0; t < 8; t++) acc[t] = fmaf(cf, (float)v[t], acc[t]);
                }
                __builtin_amdgcn_wave_barrier();
            }
            float cg = cagg[node];
            #pragma unroll
            for (int t = 0; t < 8; t++) {
                int c = glane * 8 + t;
                o[t] = (_Float16)fmaf(s_bnw[c], acc[t], s_bnu[c] * cg);
            }
        } else {
            #pragma unroll
            for (int t = 0; t < 8; t++) o[t] = (_Float16)0.0f;
        }
        *(half8*)&Alds[lrow * 136 + glane * 8] = o;
    }
    __syncthreads();

    // ---- MFMA phase ----
    int w = tid >> 6, l64 = tid & 63;
    int quad = l64 >> 4, l16 = l64 & 15;
    const half8* Bh8 = (const half8*)Whi;
    const half8* Bl8 = (const half8*)Wlo;
    f32x4 acc[8];
    #pragma unroll
    for (int j = 0; j < 8; j++) acc[j] = (f32x4){0.f, 0.f, 0.f, 0.f};
    int lrowA = w * 16 + l16;
    #pragma unroll
    for (int kc = 0; kc < 4; kc++) {
        half8 a = *(const half8*)&Alds[lrowA * 136 + kc * 32 + quad * 8];
        #pragma unroll
        for (int nt = 0; nt < 8; nt++) {
            half8 bh = Bh8[(nt * 4 + kc) * 64 + l64];
            half8 bl = Bl8[(nt * 4 + kc) * 64 + l64];
            acc[nt] = __builtin_amdgcn_mfma_f32_16x16x32_f16(a, bh, acc[nt], 0, 0, 0);
            acc[nt] = __builtin_amdgcn_mfma_f32_16x16x32_f16(a, bl, acc[nt], 0, 0, 0);
        }
    }

    // ---- epilogue: bias + rational + fp16 store + stats (C layout: col=l16, row=quad*4+reg) ----
    float ps[8], pq[8];
    #pragma unroll
    for (int nt = 0; nt < 8; nt++) { ps[nt] = 0.0f; pq[nt] = 0.0f; }
    #pragma unroll
    for (int reg = 0; reg < 4; reg++) {
        int row = r0 + w * 16 + quad * 4 + reg;
        if (row < n) {
            #pragma unroll
            for (int nt = 0; nt < 8; nt++) {
                int col = nt * 16 + l16;
                float v = acc[nt][reg] + s_bias[col];
                float r = rational_act(v, s_num + s_cl[col] * 6, s_den + s_cl[col] * 4);
                actOut[row * HID + col] = (_Float16)r;
                ps[nt] += r; pq[nt] = fmaf(r, r, pq[nt]);
            }
        }
    }
    #pragma unroll
    for (int nt = 0; nt < 8; nt++) {
        int col = nt * 16 + l16;
        atomicAdd(&s_sum[col], ps[nt]);
        atomicAdd(&s_sq[col], pq[nt]);
    }
    __syncthreads();
    if (tid < HID) {
        atomicAdd(&statOut[tid], s_sum[tid]);
        atomicAdd(&statOut[HID + tid], s_sq[tid]);
    }
}

// ---------------- fused pool (+final BN affine from stats) + 3-stage MLP ----------------
__global__ __launch_bounds__(256) void poolmlp_kernel(const _Float16* __restrict__ act,
                                                      const int* __restrict__ gstart,
                                                      const int* __restrict__ gend,
                                                      const float* __restrict__ stat,
                                                      const float* __restrict__ g3,
                                                      const float* __restrict__ be3,
                                                      const float* __restrict__ HW1,
                                                      const float* __restrict__ Hb1,
                                                      const float* __restrict__ HW2,
                                                      const float* __restrict__ Hb2,
                                                      const float* __restrict__ HW3,
                                                      const float* __restrict__ Hb3,
                                                      float* __restrict__ out, int n) {
    __shared__ float red[16][HID];
    __shared__ float s_pool[HID];
    __shared__ float s_z[HID];
    int gi = blockIdx.x;
    int tid = threadIdx.x;
    int rg = tid >> 4, lane = tid & 15;
    int s = gstart[gi], e = gend[gi];
    const half8* act8 = (const half8*)act;
    float a[8];
    #pragma unroll
    for (int t = 0; t < 8; t++) a[t] = 0.0f;
    for (int r = s + rg; r < e; r += 16) {
        half8 v = act8[r * 16 + lane];
        #pragma unroll
        for (int t = 0; t < 8; t++) a[t] += (float)v[t];
    }
    #pragma unroll
    for (int t = 0; t < 8; t++) red[rg][lane * 8 + t] = a[t];
    __syncthreads();
    if (tid < HID) {
        float tot = 0.0f;
        #pragma unroll
        for (int i = 0; i < 16; i++) tot += red[i][tid];
        int cnt = e - s;
        float pooled = 0.0f;
        if (cnt > 0) {
            float inv_n = 1.0f / (float)n;
            float mean = stat[tid] * inv_n;
            float var = stat[HID + tid] * inv_n - mean * mean;
            float w = g3[tid] * rsqrtf(var + 1e-5f);
            float u = be3[tid] - mean * w;
            pooled = fmaf(w, tot / (float)cnt, u);
        }
        s_pool[tid] = pooled;
    }
    __syncthreads();
    if (tid < HID) {
        float acc = Hb1[tid];
        #pragma unroll 8
        for (int k = 0; k < HID; k++) acc = fmaf(s_pool[k], HW1[k * HID + tid], acc);
        s_z[tid] = 0.5f * acc * (1.0f + erff(acc * 0.70710678118654752f));
    }
    __syncthreads();
    if (tid < HID) {
        float acc = Hb2[tid];
        #pragma unroll 8
        for (int k = 0; k < HID; k++) acc = fmaf(s_z[k], HW2[k * HID + tid], acc);
        s_pool[tid] = 0.5f * acc * (1.0f + erff(acc * 0.70710678118654752f));
    }
    __syncthreads();
    if (tid < OUTF) {
        float acc = Hb3[tid];
        #pragma unroll 8
        for (int k = 0; k < HID; k++) acc = fmaf(s_pool[k], HW3[k * OUTF + tid], acc);
        out[gi * OUTF + tid] = acc;
    }
}

extern "C" void kernel_launch(void* const* d_in, const int* in_sizes, int n_in,
                              void* d_out, int out_size, void* d_ws, size_t ws_size,
                              hipStream_t stream) {
    const float* x          = (const float*)d_in[0];
    const int*   edge_index = (const int*)d_in[1];
    const int*   batch      = (const int*)d_in[2];
    const float* W[4]  = {(const float*)d_in[3], (const float*)d_in[7], (const float*)d_in[11], (const float*)d_in[15]};
    const float* bL[4] = {(const float*)d_in[4], (const float*)d_in[8], (const float*)d_in[12], (const float*)d_in[16]};
    const float* gL[4] = {(const float*)d_in[5], (const float*)d_in[9], (const float*)d_in[13], (const float*)d_in[17]};
    const float* beL[4]= {(const float*)d_in[6], (const float*)d_in[10], (const float*)d_in[14], (const float*)d_in[18]};
    const float* rat_num = (const float*)d_in[19];
    const float* rat_den = (const float*)d_in[20];
    const int*   cl_assign = (const int*)d_in[21];
    const float* HW1 = (const float*)d_in[22];
    const float* Hb1 = (const float*)d_in[23];
    const float* HW2 = (const float*)d_in[24];
    const float* Hb2 = (const float*)d_in[25];
    const float* HW3 = (const float*)d_in[26];
    const float* Hb3 = (const float*)d_in[27];
    float* out = (float*)d_out;

    const int N = in_sizes[0] / INF;
    const int E = in_sizes[1] / 2;
    const int NB = (N + 1023) / 1024;

    // ---- workspace layout (dword offsets) ----
    char* wsb = (char*)d_ws;
    size_t o = 0;
    #define ALIGN16 o = (o + 3) & ~(size_t)3;
    int*   cnt     = (int*)(wsb + o * 4);  o += N; ALIGN16          // zeroed; reused as cagg
    int*   gstart  = (int*)(wsb + o * 4);  o += GRP;                // zeroed
    int*   gend    = (int*)(wsb + o * 4);  o += GRP;                // zeroed
    float* bnstat  = (float*)(wsb + o * 4); o += 4 * 256;           // zeroed
    size_t zero_elems = o;
    int*   bsum    = (int*)(wsb + o * 4);  o += ((NB + 63) & ~63); ALIGN16
    int*   cursor  = (int*)(wsb + o * 4);  o += N; ALIGN16
    int*   row_ptr = (int*)(wsb + o * 4);  o += N + 1; ALIGN16
    float* dinv    = (float*)(wsb + o * 4); o += N; ALIGN16
    int2*  csr     = (int2*)(wsb + o * 4);  o += 2 * (size_t)E; ALIGN16
    float* aggX    = (float*)(wsb + o * 4); o += (size_t)N * INF; ALIGN16
    _Float16* WhiAll = (_Float16*)(wsb + o * 4); o += 4 * HID * HID / 2; ALIGN16
    _Float16* WloAll = (_Float16*)(wsb + o * 4); o += 4 * HID * HID / 2; ALIGN16
    _Float16* act_h  = (_Float16*)(wsb + o * 4); o += (size_t)N * HID / 2;
    float* cagg = (float*)cnt;

    hipMemsetAsync(d_ws, 0, zero_elems * 4, stream);

    int eb = (E + 255) / 256;
    hist_prepw_kernel<<<eb, 256, 0, stream>>>(edge_index, cnt, E, W[1], W[2], W[3],
                                              WhiAll, WloAll);
    scanA_kernel<<<NB, 256, 0, stream>>>(cnt, bsum, N);
    scanB_kernel<<<1, 64, 0, stream>>>(bsum, row_ptr, NB, N);
    scanC_kernel<<<NB, 256, 0, stream>>>(cnt, bsum, batch, row_ptr, cursor, dinv,
                                         gstart, gend, N);
    fill_kernel<<<eb, 256, 0, stream>>>(edge_index, cursor, dinv, csr, E);

    // layer 0
    aggx_kernel<<<(N + 15) / 16, 256, 0, stream>>>(x, row_ptr, csr, dinv, aggX, cagg, N);
    gemm0_fused_kernel<<<1024, 256, 0, stream>>>(aggX, W[0], bL[0], rat_num, rat_den,
                                                 cl_assign, act_h, bnstat, N);

    int layer_grid = (N + 63) / 64;
    for (int l = 1; l < 4; l++) {
        layer_fused_kernel<<<layer_grid, 256, 0, stream>>>(act_h, csr, row_ptr, dinv, cagg,
                                                           bnstat + (l - 1) * 256,
                                                           gL[l - 1], beL[l - 1],
                                                           WhiAll + (size_t)l * HID * HID,
                                                           WloAll + (size_t)l * HID * HID,
                                                           bL[l], rat_num, rat_den, cl_assign,
                                                           act_h, bnstat + l * 256, N);
    }
    poolmlp_kernel<<<GRP, 256, 0, stream>>>(act_h, gstart, gend, bnstat + 3 * 256,
                                            gL[3], beL[3], HW1, Hb1, HW2, Hb2, HW3, Hb3,
                                            out, N);
}